// Round 1
// baseline (739.682 us; speedup 1.0000x reference)
//
#include <hip/hip_runtime.h>
#include <math.h>

#define NH    8
#define NQB   4
#define NPAIR 32
#define NTOK  1024
#define DH    64
#define DIMX  512
#define NROWS (NPAIR*NTOK)

// ---------------------------------------------------------------- utilities

__device__ __forceinline__ void gemm_micro32(const float* __restrict__ As,
    const float* __restrict__ Bs, int tx, int ty, float (&acc)[4][4]){
  #pragma unroll
  for (int kk = 0; kk < 32; kk += 4){
    float4 a0 = *(const float4*)(As + (ty*4+0)*36 + kk);
    float4 a1 = *(const float4*)(As + (ty*4+1)*36 + kk);
    float4 a2 = *(const float4*)(As + (ty*4+2)*36 + kk);
    float4 a3 = *(const float4*)(As + (ty*4+3)*36 + kk);
    float4 b0 = *(const float4*)(Bs + (kk+0)*68 + tx*4);
    float4 b1 = *(const float4*)(Bs + (kk+1)*68 + tx*4);
    float4 b2 = *(const float4*)(Bs + (kk+2)*68 + tx*4);
    float4 b3 = *(const float4*)(Bs + (kk+3)*68 + tx*4);
#define ROWMAC(AR, I) \
    acc[I][0] += AR.x*b0.x + AR.y*b1.x + AR.z*b2.x + AR.w*b3.x; \
    acc[I][1] += AR.x*b0.y + AR.y*b1.y + AR.z*b2.y + AR.w*b3.y; \
    acc[I][2] += AR.x*b0.z + AR.y*b1.z + AR.z*b2.z + AR.w*b3.z; \
    acc[I][3] += AR.x*b0.w + AR.y*b1.w + AR.z*b2.w + AR.w*b3.w;
    ROWMAC(a0,0) ROWMAC(a1,1) ROWMAC(a2,2) ROWMAC(a3,3)
#undef ROWMAC
  }
}

// ------------------------------------------------- per-token LN statistics

__global__ __launch_bounds__(256) void k_lnstats(const float* __restrict__ q,
    const float* __restrict__ k, const float* __restrict__ v,
    float* __restrict__ mu_rstd){
  int wid = threadIdx.x >> 6, lane = threadIdx.x & 63;
  int tok = blockIdx.x*4 + wid;            // 0..12287
  const float* src = (tok < 4096) ? q : ((tok < 8192) ? k : v);
  int t = tok & 4095;
  const float4* p4 = (const float4*)(src + (size_t)t*DIMX) + lane*2;
  float4 a = p4[0], b = p4[1];
  float s  = a.x+a.y+a.z+a.w + b.x+b.y+b.z+b.w;
  float ss = a.x*a.x+a.y*a.y+a.z*a.z+a.w*a.w
           + b.x*b.x+b.y*b.y+b.z*b.z+b.w*b.w;
  #pragma unroll
  for (int off=32; off; off>>=1){ s += __shfl_down(s,off); ss += __shfl_down(ss,off); }
  if (lane==0){
    float mu = s*(1.0f/512.0f);
    float var = ss*(1.0f/512.0f) - mu*mu;
    mu_rstd[tok*2+0] = mu;
    mu_rstd[tok*2+1] = 1.0f/sqrtf(var + 1e-5f);
  }
}

// ----------------------------------- LN + projection GEMM (q, k, v fused-z)

__global__ __launch_bounds__(256) void k_proj(
    const float* __restrict__ q, const float* __restrict__ k, const float* __restrict__ v,
    const float* __restrict__ g, const float* __restrict__ bln,
    const float* __restrict__ W, const float* __restrict__ mu_rstd,
    float* __restrict__ fq, float* __restrict__ fk, float* __restrict__ fv,
    double* __restrict__ qgs, double* __restrict__ kgs){
  __shared__ float As[64*36];
  __shared__ float Bs[32*68];
  int z = blockIdx.z;
  const float* x = (z==0) ? q : ((z==1) ? k : v);
  float* fo = (z==0) ? fq : ((z==1) ? fk : fv);
  int tb = blockIdx.x;         // token tile (64 tokens)
  int hb = blockIdx.y;         // head / 64-col tile
  int tid = threadIdx.x;
  int tx = tid & 15, ty = tid >> 4;
  float acc[4][4] = {};
  for (int kc = 0; kc < 16; ++kc){
    #pragma unroll
    for (int i = 0; i < 2; ++i){
      int idx4 = tid + 256*i;               // 0..511
      int r = idx4 >> 3, k4 = idx4 & 7;
      int tokg = z*4096 + tb*64 + r;
      float mu = mu_rstd[tokg*2+0], rstd = mu_rstd[tokg*2+1];
      float4 xv = *(const float4*)(x + (size_t)(tb*64+r)*DIMX + kc*32 + k4*4);
      float4 gv = *(const float4*)(g   + kc*32 + k4*4);
      float4 bv = *(const float4*)(bln + kc*32 + k4*4);
      float4 yv;
      yv.x = (xv.x-mu)*rstd*gv.x + bv.x;
      yv.y = (xv.y-mu)*rstd*gv.y + bv.y;
      yv.z = (xv.z-mu)*rstd*gv.z + bv.z;
      yv.w = (xv.w-mu)*rstd*gv.w + bv.w;
      *(float4*)(As + r*36 + k4*4) = yv;
    }
    #pragma unroll
    for (int i = 0; i < 2; ++i){
      int idx4 = tid + 256*i;
      int kr = idx4 >> 4, c4 = idx4 & 15;
      *(float4*)(Bs + kr*68 + c4*4) =
          *(const float4*)(W + (size_t)(kc*32+kr)*DIMX + hb*64 + c4*4);
    }
    __syncthreads();
    gemm_micro32(As, Bs, tx, ty, acc);
    __syncthreads();
  }
  #pragma unroll
  for (int i = 0; i < 4; ++i){
    int t = tb*64 + ty*4 + i;
    int qb = t >> 10, n = t & 1023;
    int p = hb*4 + qb;
    float4 o = make_float4(acc[i][0], acc[i][1], acc[i][2], acc[i][3]);
    *(float4*)(fo + (size_t)(p*NTOK + n)*DH + tx*4) = o;
  }
  if (z < 2){
    __syncthreads();
    float* scr = As;   // 64 cols x 16 ty
    #pragma unroll
    for (int j = 0; j < 4; ++j){
      float cs = acc[0][j]+acc[1][j]+acc[2][j]+acc[3][j];
      scr[(tx*4+j)*16 + ty] = cs;
    }
    __syncthreads();
    if (tid < 64){
      float tot = 0.f;
      #pragma unroll
      for (int e = 0; e < 16; ++e) tot += scr[tid*16+e];
      double* dst = (z==0) ? qgs : kgs;
      atomicAdd(&dst[hb*64 + tid], (double)tot);
    }
  }
}

// -------------------------------------------- nu (col-means of f_k) and S

__global__ __launch_bounds__(256) void k_nu(const float* __restrict__ fk,
    float* __restrict__ nuA, float* __restrict__ Sarr){
  __shared__ float red[4][64];
  int p = blockIdx.x, tid = threadIdx.x;
  int td = tid & 63, tm = tid >> 6;
  float s = 0.f;
  for (int m = tm; m < NTOK; m += 4) s += fk[(size_t)(p*NTOK+m)*DH + td];
  red[tm][td] = s;
  __syncthreads();
  if (tid < 64){
    float tot = red[0][tid]+red[1][tid]+red[2][tid]+red[3][tid];
    float nuv = tot * (1.0f/1024.0f);
    nuA[p*DH+tid] = nuv;
    float sv = nuv;
    #pragma unroll
    for (int off=32; off; off>>=1) sv += __shfl_down(sv, off);
    if (tid==0) Sarr[p] = sv;
  }
}

// --------------------------------------- per-row scalars for f_q and f_k

__global__ __launch_bounds__(256) void k_rows(const float* __restrict__ fq,
    const float* __restrict__ fk, const float* __restrict__ nuA,
    float* __restrict__ inv_na_q, float* __restrict__ inv_nb_q,
    float* __restrict__ muqA, float* __restrict__ tqA,
    float* __restrict__ inv_na_k, float* __restrict__ inv_nb_k,
    float* __restrict__ skA){
  int wid = threadIdx.x >> 6, lane = threadIdx.x & 63;
  int row = blockIdx.x*4 + wid;            // < 32768
  int p = row >> 10;
  float xq = fq[(size_t)row*DH + lane];
  float nv = nuA[p*DH + lane];
  float s = xq, ss = xq*xq, sd = xq*nv;
  #pragma unroll
  for (int off=32; off; off>>=1){
    s += __shfl_down(s,off); ss += __shfl_down(ss,off); sd += __shfl_down(sd,off);
  }
  if (lane==0){
    float nrm = sqrtf(ss);
    inv_na_q[row] = 1.0f/(nrm+1e-8f);
    inv_nb_q[row] = 1.0f/fmaxf(nrm,1e-6f);
    muqA[row] = s*(1.0f/64.0f);
    tqA[row] = sd;
  }
  float xk = fk[(size_t)row*DH + lane];
  float s2 = xk, ss2 = xk*xk;
  #pragma unroll
  for (int off=32; off; off>>=1){
    s2 += __shfl_down(s2,off); ss2 += __shfl_down(ss2,off);
  }
  if (lane==0){
    float nrm = sqrtf(ss2);
    inv_na_k[row] = 1.0f/(nrm+1e-8f);
    inv_nb_k[row] = 1.0f/fmaxf(nrm,1e-6f);
    skA[row] = s2;
  }
}

// ------------------------------------------------- weight predictor (tiny)

__global__ __launch_bounds__(256) void k_wp(const double* __restrict__ qgs,
    const double* __restrict__ kgs,
    const float* __restrict__ W1, const float* __restrict__ b1,
    const float* __restrict__ lgv, const float* __restrict__ lbv,
    const float* __restrict__ W2, const float* __restrict__ b2,
    const float* __restrict__ W3, const float* __restrict__ b3,
    const float* __restrict__ wtemp, float* __restrict__ wp_out){
  __shared__ float feats[8][128];
  __shared__ float h1[8][64];
  __shared__ float h2s[8][32];
  __shared__ float lgt[8][3];
  __shared__ float mv[8][2];
  int tid = threadIdx.x;
  for (int idx = tid; idx < 1024; idx += 256){
    int h = idx >> 7, i = idx & 127;
    double vv = (i < 64) ? qgs[h*64+i] : kgs[h*64+(i-64)];
    feats[h][i] = (float)(vv * (1.0/4096.0));
  }
  __syncthreads();
  for (int idx = tid; idx < 512; idx += 256){
    int h = idx >> 6, j = idx & 63;
    float s = b1[j];
    for (int i = 0; i < 128; ++i) s += feats[h][i]*W1[i*64+j];
    h1[h][j] = s;
  }
  __syncthreads();
  if (tid < 8){
    float s=0.f, ss=0.f;
    for (int j=0;j<64;++j){ float vv=h1[tid][j]; s+=vv; ss+=vv*vv; }
    float mu = s*(1.0f/64.0f);
    float var = ss*(1.0f/64.0f)-mu*mu;
    mv[tid][0]=mu; mv[tid][1]=1.0f/sqrtf(var+1e-5f);
  }
  __syncthreads();
  for (int idx = tid; idx < 512; idx += 256){
    int h = idx>>6, j = idx&63;
    float vv = (h1[h][j]-mv[h][0])*mv[h][1]*lgv[j] + lbv[j];
    h1[h][j] = fmaxf(vv, 0.f);
  }
  __syncthreads();
  {
    int h = tid >> 5, j = tid & 31;
    float s = b2[j];
    for (int i=0;i<64;++i) s += h1[h][i]*W2[i*32+j];
    h2s[h][j] = fmaxf(s, 0.f);
  }
  __syncthreads();
  if (tid < 24){
    int h = tid/3, j = tid - h*3;
    float s = b3[j];
    for (int i=0;i<32;++i) s += h2s[h][i]*W3[i*3+j];
    lgt[h][j] = s;
  }
  __syncthreads();
  if (tid < 8){
    int h = tid;
    float z0=lgt[h][0], z1=lgt[h][1], z2=lgt[h][2];
    float m = fmaxf(z0,fmaxf(z1,z2));
    float e0=expf(z0-m), e1=expf(z1-m), e2=expf(z2-m);
    float inv = 1.0f/(e0+e1+e2);
    float l0=e0*inv, l1=e1*inv, l2=e2*inv;
    float wt = fminf(fmaxf(wtemp[0], 0.1f), 20.0f);
    float y0=l0/wt, y1=l1/wt, y2=l2/wt;
    float m2 = fmaxf(y0,fmaxf(y1,y2));
    float f0=expf(y0-m2), f1=expf(y1-m2), f2=expf(y2-m2);
    float inv2 = 1.0f/(f0+f1+f2);
    float w0=f0*inv2, w1=f1*inv2, w2=f2*inv2;
    w0 = fminf(fmaxf(w0,0.05f),0.8f);
    w1 = fminf(fmaxf(w1,0.05f),0.8f);
    w2 = fminf(fmaxf(w2,0.05f),0.8f);
    float isum = 1.0f/(w0+w1+w2);
    wp_out[h*3+0]=w0*isum; wp_out[h*3+1]=w1*isum; wp_out[h*3+2]=w2*isum;
  }
}

// ------------------------- pass A: QK^T, derive cos/cov/margin, statistics

__global__ __launch_bounds__(256) void k_passA(
    const float* __restrict__ fq, const float* __restrict__ fk,
    const float* __restrict__ inv_na_q, const float* __restrict__ inv_nb_q,
    const float* __restrict__ muqA, const float* __restrict__ tqA,
    const float* __restrict__ inv_na_k, const float* __restrict__ inv_nb_k,
    const float* __restrict__ skA, const float* __restrict__ Sarr,
    float* __restrict__ rs_cos, float* __restrict__ rs_cov, float* __restrict__ rs_marg,
    float* __restrict__ mxcosA, float* __restrict__ mncosA,
    float* __restrict__ mxcovA, float* __restrict__ mncovA,
    double* __restrict__ gacc){
  __shared__ float fqL[32*68];
  __shared__ float fkL[64*68];
  __shared__ float rA[32], rB[32], rM[32], rT[32];
  __shared__ float cA[64], cB[64], cS[64];
  __shared__ float rowred[7][32][8];
  __shared__ double wredS[4][5];
  int b = blockIdx.x;
  int p = b >> 5, s = b & 31;
  int n0 = s*32;
  int tid = threadIdx.x;
  const float4* fq4 = (const float4*)(fq + (size_t)(p*NTOK + n0)*DH);
  #pragma unroll
  for (int i = 0; i < 2; ++i){
    int idx4 = tid + 256*i;
    int r = idx4 >> 4, d4 = idx4 & 15;
    *(float4*)(fqL + r*68 + d4*4) = fq4[r*16 + d4];
  }
  if (tid < 32){
    int row = p*NTOK + n0 + tid;
    rA[tid] = inv_na_q[row]; rB[tid] = inv_nb_q[row];
    rM[tid] = muqA[row];     rT[tid] = tqA[row];
  }
  float Sp = Sarr[p];
  int r = tid >> 3, ct = tid & 7;
  const float inv8 = (float)(1.0/(8.0+1e-6));
  double a_c1=0,a_c2=0,a_v1=0,a_v2=0,a_cv=0;
  float p_cos=0.f, p_cov=0.f, p_marg=0.f;
  float p_mxc=-1e30f, p_mnc=1e30f, p_mxv=-1e30f, p_mnv=1e30f;
  for (int cc = 0; cc < 16; ++cc){
    int m0 = cc*64;
    const float4* fk4 = (const float4*)(fk + (size_t)(p*NTOK + m0)*DH);
    #pragma unroll
    for (int i = 0; i < 4; ++i){
      int idx4 = tid + 256*i;
      int m = idx4 >> 4, d4 = idx4 & 15;
      *(float4*)(fkL + m*68 + d4*4) = fk4[m*16 + d4];
    }
    if (tid < 64){
      int row = p*NTOK + m0 + tid;
      cA[tid] = inv_na_k[row]; cB[tid] = inv_nb_k[row]; cS[tid] = skA[row];
    }
    __syncthreads();
    float acc[8] = {0,0,0,0,0,0,0,0};
    #pragma unroll
    for (int d4 = 0; d4 < 16; ++d4){
      float4 av = *(const float4*)(fqL + r*68 + d4*4);
      #pragma unroll
      for (int j = 0; j < 8; ++j){
        float4 bv = *(const float4*)(fkL + (ct+8*j)*68 + d4*4);
        acc[j] += av.x*bv.x + av.y*bv.y + av.z*bv.z + av.w*bv.w;
      }
    }
    float ia = rA[r], ib = rB[r], mq = rM[r], tq = rT[r];
    #pragma unroll
    for (int j = 0; j < 8; ++j){
      int c = ct + 8*j;
      float dot = acc[j];
      float cosv = fminf(fmaxf(dot * ia * cA[c], -0.99f), 0.99f);
      float csim = fminf(fmaxf(dot * ib * cB[c], -0.99f), 0.99f);
      float marg = fminf(fmaxf(0.01f - csim, 0.f), 10.f);
      float cov  = (dot - tq - mq*cS[c] + mq*Sp) * inv8;
      a_c1 += (double)cosv;           a_c2 += (double)cosv*(double)cosv;
      a_v1 += (double)cov;            a_v2 += (double)cov*(double)cov;
      a_cv += (double)cosv*(double)cov;
      p_cos += cosv; p_cov += cov; p_marg += marg;
      p_mxc = fmaxf(p_mxc, cosv); p_mnc = fminf(p_mnc, cosv);
      p_mxv = fmaxf(p_mxv, cov);  p_mnv = fminf(p_mnv, cov);
    }
    __syncthreads();
  }
  rowred[0][r][ct] = p_cos; rowred[1][r][ct] = p_cov; rowred[2][r][ct] = p_marg;
  rowred[3][r][ct] = p_mxc; rowred[4][r][ct] = p_mnc;
  rowred[5][r][ct] = p_mxv; rowred[6][r][ct] = p_mnv;
  __syncthreads();
  if (tid < 32){
    float sc=0.f, sv=0.f, sm=0.f, xc=-1e30f, nc=1e30f, xv=-1e30f, nv2=1e30f;
    #pragma unroll
    for (int e = 0; e < 8; ++e){
      sc += rowred[0][tid][e]; sv += rowred[1][tid][e]; sm += rowred[2][tid][e];
      xc = fmaxf(xc, rowred[3][tid][e]); nc = fminf(nc, rowred[4][tid][e]);
      xv = fmaxf(xv, rowred[5][tid][e]); nv2 = fminf(nv2, rowred[6][tid][e]);
    }
    int row = p*NTOK + n0 + tid;
    rs_cos[row]=sc; rs_cov[row]=sv; rs_marg[row]=sm;
    mxcosA[row]=xc; mncosA[row]=nc; mxcovA[row]=xv; mncovA[row]=nv2;
  }
  double vals[5] = {a_c1,a_c2,a_v1,a_v2,a_cv};
  int lane = tid & 63, wid = tid >> 6;
  #pragma unroll
  for (int c2 = 0; c2 < 5; ++c2){
    double vv = vals[c2];
    #pragma unroll
    for (int off=32; off; off>>=1) vv += __shfl_down(vv, off);
    if (lane==0) wredS[wid][c2] = vv;
  }
  __syncthreads();
  if (tid == 0){
    int h = p >> 2;
    #pragma unroll
    for (int c2 = 0; c2 < 5; ++c2){
      double t = wredS[0][c2]+wredS[1][c2]+wredS[2][c2]+wredS[3][c2];
      atomicAdd(&gacc[h*5+c2], t);
    }
  }
}

// ---------------------- row finish: var_row + var-related global moments

__global__ __launch_bounds__(256) void k_rowfin(const float* __restrict__ rs_cos,
    const float* __restrict__ rs_cov, const float* __restrict__ rs_marg,
    float* __restrict__ var_row, double* __restrict__ racc){
  __shared__ double wredS[4][4];
  int row = blockIdx.x*256 + threadIdx.x;
  int p = row >> 10; int h = p >> 2;
  float vr = rs_marg[row] * (1.0f/1024.0f);
  var_row[row] = vr;
  double dv = (double)vr;
  double vals[4];
  vals[0] = 1024.0*dv;
  vals[1] = 1024.0*dv*dv;
  vals[2] = dv*(double)rs_cos[row];
  vals[3] = dv*(double)rs_cov[row];
  int lane = threadIdx.x & 63, wid = threadIdx.x >> 6;
  #pragma unroll
  for (int c2 = 0; c2 < 4; ++c2){
    double vv = vals[c2];
    #pragma unroll
    for (int off=32; off; off>>=1) vv += __shfl_down(vv, off);
    if (lane==0) wredS[wid][c2] = vv;
  }
  __syncthreads();
  if (threadIdx.x == 0){
    #pragma unroll
    for (int c2 = 0; c2 < 4; ++c2){
      double t = wredS[0][c2]+wredS[1][c2]+wredS[2][c2]+wredS[3][c2];
      atomicAdd(&racc[h*4+c2], t);
    }
  }
}

// ------------------------------------- finalize scalars -> d2 coefficients

__global__ void k_final(const double* __restrict__ gacc, const double* __restrict__ racc,
                        const float* __restrict__ wp_out, float* __restrict__ coef){
  if (threadIdx.x != 0) return;
  const double N = 33554432.0;
  double Sc1=0,Sc2=0,Sv1=0,Sv2=0,Sr1=0,Sr2=0;
  for (int h=0;h<8;++h){
    Sc1+=gacc[h*5+0]; Sc2+=gacc[h*5+1]; Sv1+=gacc[h*5+2]; Sv2+=gacc[h*5+3];
    Sr1+=racc[h*4+0]; Sr2+=racc[h*4+1];
  }
  double cvar = (Sc2 - Sc1*Sc1/N)/(N-1.0);
  double cn = sqrt(fmax(cvar,0.0)) + 1e-6;
  double cscale = (cn < 1e-4) ? 0.1 : 1.0;
  double vraw = (Sv2 - Sv1*Sv1/N)/(N-1.0);
  double sraw = sqrt(fmax(vraw,0.0));
  double basev = 0.001/1024.0;
  double regv = (sraw < 1e-6) ? basev*10.0 : basev;
  double covn = regv*sraw + 1e-6;
  double vvar = (Sr2 - Sr1*Sr1/N)/(N-1.0);
  double vn = sqrt(fmax(vvar,0.0)) + 1e-6;
  double ah[8], bh[8], chh[8];
  double Sd1=0.0, Sd2=0.0;
  for (int h=0;h<8;++h){
    double a = (double)wp_out[h*3+0]/cn*cscale;
    double b = (double)wp_out[h*3+1]*regv*0.5/covn;
    double c = (double)wp_out[h*3+2]*0.5/vn;
    ah[h]=a; bh[h]=b; chh[h]=c;
    Sd1 += a*gacc[h*5+0] + b*gacc[h*5+2] + c*racc[h*4+0];
    Sd2 += a*a*gacc[h*5+1] + b*b*gacc[h*5+3] + c*c*racc[h*4+1]
         + 2.0*(a*b*gacc[h*5+4] + a*c*racc[h*4+2] + b*c*racc[h*4+3]);
  }
  double dvar = (Sd2 - Sd1*Sd1/N)/(N-1.0);
  double dstd = sqrt(fmax(dvar,0.0));
  double temp = (dstd < 1e-6) ? 0.1 : 0.3 + dstd;
  double tcl = fmin(fmax(temp,0.1),5.0);
  double it = 1.0/tcl;
  for (int h=0;h<8;++h){
    coef[h*3+0] = (float)(ah[h]*it);
    coef[h*3+1] = (float)(bh[h]*it);
    coef[h*3+2] = (float)(chh[h]*it);
  }
}

// -------------------- pass C: recompute QK, softmax via bound, PV, output

__global__ __launch_bounds__(256) void k_pv(
    const float* __restrict__ fq, const float* __restrict__ fk, const float* __restrict__ fv,
    const float* __restrict__ inv_na_q, const float* __restrict__ inv_nb_q,
    const float* __restrict__ muqA, const float* __restrict__ tqA,
    const float* __restrict__ inv_na_k, const float* __restrict__ inv_nb_k,
    const float* __restrict__ skA, const float* __restrict__ Sarr,
    const float* __restrict__ var_row,
    const float* __restrict__ mxcosA, const float* __restrict__ mncosA,
    const float* __restrict__ mxcovA, const float* __restrict__ mncovA,
    const float* __restrict__ coef, float* __restrict__ oh){
  __shared__ float fqL[32*68];
  __shared__ float fkL[64*68];
  __shared__ float fvT[64*68];
  __shared__ float eL[32*68];
  __shared__ float rA[32], rB2[32], rM[32], rT[32], rV[32], rMh[32], rDen[32];
  __shared__ float cA[64], cB[64], cS[64];
  int b = blockIdx.x; int p = b>>5, s = b&31; int n0 = s*32;
  int h = p >> 2, qb = p & 3;
  int tid = threadIdx.x;
  float A = coef[h*3+0], B = coef[h*3+1], C = coef[h*3+2];
  const float4* fq4 = (const float4*)(fq + (size_t)(p*NTOK + n0)*DH);
  #pragma unroll
  for (int i = 0; i < 2; ++i){
    int idx4 = tid + 256*i;
    int r = idx4 >> 4, d4 = idx4 & 15;
    *(float4*)(fqL + r*68 + d4*4) = fq4[r*16 + d4];
  }
  if (tid < 32){
    int row = p*NTOK + n0 + tid;
    rA[tid]=inv_na_q[row]; rB2[tid]=inv_nb_q[row];
    rM[tid]=muqA[row];     rT[tid]=tqA[row];
    float vr = var_row[row]; rV[tid] = vr;
    float Mh = fmaxf(A*mxcosA[row], A*mncosA[row])
             + fmaxf(B*mxcovA[row], B*mncovA[row]) + C*vr;
    rMh[tid] = Mh;
  }
  float Sp = Sarr[p];
  int r = tid >> 3, ct = tid & 7;
  const float inv8 = (float)(1.0/(8.0+1e-6));
  float outacc[8] = {0,0,0,0,0,0,0,0};
  float den_t = 0.f;
  for (int cc = 0; cc < 16; ++cc){
    int m0 = cc*64;
    const float4* fk4 = (const float4*)(fk + (size_t)(p*NTOK + m0)*DH);
    #pragma unroll
    for (int i = 0; i < 4; ++i){
      int idx4 = tid + 256*i;
      int m = idx4 >> 4, d4 = idx4 & 15;
      *(float4*)(fkL + m*68 + d4*4) = fk4[m*16 + d4];
    }
    const float4* fv4 = (const float4*)(fv + (size_t)(p*NTOK + m0)*DH);
    #pragma unroll
    for (int i = 0; i < 4; ++i){
      int idx4 = tid + 256*i;
      int m = idx4 >> 4, d4 = idx4 & 15;
      float4 vv = fv4[m*16 + d4];
      fvT[(d4*4+0)*68 + m] = vv.x;
      fvT[(d4*4+1)*68 + m] = vv.y;
      fvT[(d4*4+2)*68 + m] = vv.z;
      fvT[(d4*4+3)*68 + m] = vv.w;
    }
    if (tid < 64){
      int row = p*NTOK + m0 + tid;
      cA[tid] = inv_na_k[row]; cB[tid] = inv_nb_k[row]; cS[tid] = skA[row];
    }
    __syncthreads();
    float acc[8] = {0,0,0,0,0,0,0,0};
    #pragma unroll
    for (int d4 = 0; d4 < 16; ++d4){
      float4 av = *(const float4*)(fqL + r*68 + d4*4);
      #pragma unroll
      for (int j = 0; j < 8; ++j){
        float4 bv = *(const float4*)(fkL + (ct+8*j)*68 + d4*4);
        acc[j] += av.x*bv.x + av.y*bv.y + av.z*bv.z + av.w*bv.w;
      }
    }
    {
      float ia = rA[r], ib = rB2[r], mq = rM[r], tq = rT[r];
      float Cv = C*rV[r], Mh = rMh[r];
      (void)ib;
      #pragma unroll
      for (int j = 0; j < 8; ++j){
        int c = ct + 8*j;
        float dot = acc[j];
        float cosv = fminf(fmaxf(dot * ia * cA[c], -0.99f), 0.99f);
        float cov  = (dot - tq - mq*cS[c] + mq*Sp) * inv8;
        float d2 = A*cosv + B*cov + Cv;
        float e = expf(d2 - Mh);
        den_t += e;
        eL[r*68 + c] = e;
      }
    }
    __syncthreads();
    #pragma unroll
    for (int m4 = 0; m4 < 16; ++m4){
      float4 ev = *(const float4*)(eL + r*68 + m4*4);
      #pragma unroll
      for (int j = 0; j < 8; ++j){
        float4 fvv = *(const float4*)(fvT + (ct+8*j)*68 + m4*4);
        outacc[j] += ev.x*fvv.x + ev.y*fvv.y + ev.z*fvv.z + ev.w*fvv.w;
      }
    }
    __syncthreads();
  }
  float* scr = fkL;
  scr[r*8+ct] = den_t;
  __syncthreads();
  if (tid < 32){
    float dsum = 0.f;
    #pragma unroll
    for (int e = 0; e < 8; ++e) dsum += scr[tid*8+e];
    rDen[tid] = dsum;
  }
  __syncthreads();
  float invden = 1.0f/rDen[r];
  int n = n0 + r;
  float* dst = oh + ((size_t)(qb*NTOK + n)*NH + h)*DH;
  #pragma unroll
  for (int j = 0; j < 8; ++j) dst[ct+8*j] = outacc[j]*invden;
}

// ------------------------------------------- output GEMM: oh @ W_out + b

__global__ __launch_bounds__(256) void k_out(const float* __restrict__ Ain,
    const float* __restrict__ W, const float* __restrict__ bias,
    float* __restrict__ out){
  __shared__ float As[64*36];
  __shared__ float Bs[32*68];
  int tb = blockIdx.x, cb = blockIdx.y;
  int tid = threadIdx.x;
  int tx = tid & 15, ty = tid >> 4;
  float acc[4][4] = {};
  for (int kc = 0; kc < 16; ++kc){
    #pragma unroll
    for (int i = 0; i < 2; ++i){
      int idx4 = tid + 256*i;
      int r = idx4 >> 3, k4 = idx4 & 7;
      *(float4*)(As + r*36 + k4*4) =
          *(const float4*)(Ain + (size_t)(tb*64+r)*DIMX + kc*32 + k4*4);
    }
    #pragma unroll
    for (int i = 0; i < 2; ++i){
      int idx4 = tid + 256*i;
      int kr = idx4 >> 4, c4 = idx4 & 15;
      *(float4*)(Bs + kr*68 + c4*4) =
          *(const float4*)(W + (size_t)(kc*32+kr)*DIMX + cb*64 + c4*4);
    }
    __syncthreads();
    gemm_micro32(As, Bs, tx, ty, acc);
    __syncthreads();
  }
  float4 bv = *(const float4*)(bias + cb*64 + tx*4);
  #pragma unroll
  for (int i = 0; i < 4; ++i){
    int t = tb*64 + ty*4 + i;
    float4 o = make_float4(acc[i][0]+bv.x, acc[i][1]+bv.y, acc[i][2]+bv.z, acc[i][3]+bv.w);
    *(float4*)(out + (size_t)t*DIMX + cb*64 + tx*4) = o;
  }
}

// ----------------------------------------------------------------- launch

extern "C" void kernel_launch(void* const* d_in, const int* in_sizes, int n_in,
                              void* d_out, int out_size, void* d_ws, size_t ws_size,
                              hipStream_t stream) {
  (void)in_sizes; (void)n_in; (void)out_size;
  const float* q     = (const float*)d_in[0];
  const float* k     = (const float*)d_in[1];
  const float* v     = (const float*)d_in[2];
  const float* ln_g  = (const float*)d_in[3];
  const float* ln_b  = (const float*)d_in[4];
  const float* W_in  = (const float*)d_in[5];
  const float* wp_W1 = (const float*)d_in[6];
  const float* wp_b1 = (const float*)d_in[7];
  const float* wp_lg = (const float*)d_in[8];
  const float* wp_lb = (const float*)d_in[9];
  const float* wp_W2 = (const float*)d_in[10];
  const float* wp_b2 = (const float*)d_in[11];
  const float* wp_W3 = (const float*)d_in[12];
  const float* wp_b3 = (const float*)d_in[13];
  const float* wtemp = (const float*)d_in[14];
  const float* W_out = (const float*)d_in[15];
  const float* b_out = (const float*)d_in[16];
  float* out = (float*)d_out;

  char* wsb = (char*)d_ws;
  double* gacc = (double*)wsb;            // 40 doubles
  double* racc = gacc + 40;               // 32
  double* qgs  = racc + 32;               // 512
  double* kgs  = qgs + 512;               // 512  (zone0 total 8768 B)
  float* fqA = (float*)(wsb + 16384);
  float* fkA = fqA + (size_t)NPAIR*NTOK*DH;
  float* fvA = fkA + (size_t)NPAIR*NTOK*DH;
  float* mu_rstd = fvA + (size_t)NPAIR*NTOK*DH;   // 24576
  float* nuA  = mu_rstd + 24576;          // 2048
  float* Sarr = nuA + 2048;               // 64 (padded)
  float* inv_na_q = Sarr + 64;
  float* inv_nb_q = inv_na_q + NROWS;
  float* muqA     = inv_nb_q + NROWS;
  float* tqA      = muqA + NROWS;
  float* inv_na_k = tqA + NROWS;
  float* inv_nb_k = inv_na_k + NROWS;
  float* skA      = inv_nb_k + NROWS;
  float* rs_cos   = skA + NROWS;
  float* rs_cov   = rs_cos + NROWS;
  float* rs_marg  = rs_cov + NROWS;
  float* var_row  = rs_marg + NROWS;
  float* mxcos    = var_row + NROWS;
  float* mncos    = mxcos + NROWS;
  float* mxcov    = mncos + NROWS;
  float* mncov    = mxcov + NROWS;
  float* wp_out   = mncov + NROWS;        // 32 (padded)
  float* coef     = wp_out + 32;          // 32 (padded)
  float* oh       = coef + 32;            // 2097152

  size_t need = (size_t)((char*)(oh + (size_t)NPAIR*NTOK*DH) - wsb);
  if (ws_size < need) return;  // cannot run; fail cleanly rather than corrupt

  hipMemsetAsync(wsb, 0, 16384, stream);
  k_lnstats<<<3072, 256, 0, stream>>>(q, k, v, mu_rstd);
  k_proj<<<dim3(64,8,3), 256, 0, stream>>>(q, k, v, ln_g, ln_b, W_in, mu_rstd,
                                           fqA, fkA, fvA, qgs, kgs);
  k_nu<<<32, 256, 0, stream>>>(fkA, nuA, Sarr);
  k_rows<<<8192, 256, 0, stream>>>(fqA, fkA, nuA, inv_na_q, inv_nb_q, muqA, tqA,
                                   inv_na_k, inv_nb_k, skA);
  k_wp<<<1, 256, 0, stream>>>(qgs, kgs, wp_W1, wp_b1, wp_lg, wp_lb,
                              wp_W2, wp_b2, wp_W3, wp_b3, wtemp, wp_out);
  k_passA<<<1024, 256, 0, stream>>>(fqA, fkA, inv_na_q, inv_nb_q, muqA, tqA,
                                    inv_na_k, inv_nb_k, skA, Sarr,
                                    rs_cos, rs_cov, rs_marg,
                                    mxcos, mncos, mxcov, mncov, gacc);
  k_rowfin<<<128, 256, 0, stream>>>(rs_cos, rs_cov, rs_marg, var_row, racc);
  k_final<<<1, 64, 0, stream>>>(gacc, racc, wp_out, coef);
  k_pv<<<1024, 256, 0, stream>>>(fqA, fkA, fvA, inv_na_q, inv_nb_q, muqA, tqA,
                                 inv_na_k, inv_nb_k, skA, Sarr, var_row,
                                 mxcos, mncos, mxcov, mncov, coef, oh);
  k_out<<<dim3(64,8), 256, 0, stream>>>(oh, W_out, b_out, out);
}

// Round 2
// 551.786 us; speedup vs baseline: 1.3405x; 1.3405x over previous
//
#include <hip/hip_runtime.h>
#include <math.h>

#define NH    8
#define NQB   4
#define NPAIR 32
#define NTOK  1024
#define DH    64
#define DIMX  512
#define NROWS (NPAIR*NTOK)

typedef __attribute__((ext_vector_type(8))) short short8;
typedef __attribute__((ext_vector_type(4))) float f32x4;

__device__ __forceinline__ unsigned short f2bf(float x){
  unsigned u = __float_as_uint(x);
  u += 0x7fffu + ((u>>16)&1u);
  return (unsigned short)(u>>16);
}
__device__ __forceinline__ float bf2f(unsigned short h){
  return __uint_as_float(((unsigned)h)<<16);
}
__device__ __forceinline__ f32x4 mfma16(short8 a, short8 b, f32x4 c){
  return __builtin_amdgcn_mfma_f32_16x16x32_bf16(a,b,c,0,0,0);
}

// ---------------------------------------------------------------- utilities

__device__ __forceinline__ void gemm_micro32(const float* __restrict__ As,
    const float* __restrict__ Bs, int tx, int ty, float (&acc)[4][4]){
  #pragma unroll
  for (int kk = 0; kk < 32; kk += 4){
    float4 a0 = *(const float4*)(As + (ty*4+0)*36 + kk);
    float4 a1 = *(const float4*)(As + (ty*4+1)*36 + kk);
    float4 a2 = *(const float4*)(As + (ty*4+2)*36 + kk);
    float4 a3 = *(const float4*)(As + (ty*4+3)*36 + kk);
    float4 b0 = *(const float4*)(Bs + (kk+0)*68 + tx*4);
    float4 b1 = *(const float4*)(Bs + (kk+1)*68 + tx*4);
    float4 b2 = *(const float4*)(Bs + (kk+2)*68 + tx*4);
    float4 b3 = *(const float4*)(Bs + (kk+3)*68 + tx*4);
#define ROWMAC(AR, I) \
    acc[I][0] += AR.x*b0.x + AR.y*b1.x + AR.z*b2.x + AR.w*b3.x; \
    acc[I][1] += AR.x*b0.y + AR.y*b1.y + AR.z*b2.y + AR.w*b3.y; \
    acc[I][2] += AR.x*b0.z + AR.y*b1.z + AR.z*b2.z + AR.w*b3.z; \
    acc[I][3] += AR.x*b0.w + AR.y*b1.w + AR.z*b2.w + AR.w*b3.w;
    ROWMAC(a0,0) ROWMAC(a1,1) ROWMAC(a2,2) ROWMAC(a3,3)
#undef ROWMAC
  }
}

// ------------------------------------------------- per-token LN statistics

__global__ __launch_bounds__(256) void k_lnstats(const float* __restrict__ q,
    const float* __restrict__ k, const float* __restrict__ v,
    float* __restrict__ mu_rstd){
  int wid = threadIdx.x >> 6, lane = threadIdx.x & 63;
  int tok = blockIdx.x*4 + wid;            // 0..12287
  const float* src = (tok < 4096) ? q : ((tok < 8192) ? k : v);
  int t = tok & 4095;
  const float4* p4 = (const float4*)(src + (size_t)t*DIMX) + lane*2;
  float4 a = p4[0], b = p4[1];
  float s  = a.x+a.y+a.z+a.w + b.x+b.y+b.z+b.w;
  float ss = a.x*a.x+a.y*a.y+a.z*a.z+a.w*a.w
           + b.x*b.x+b.y*b.y+b.z*b.z+b.w*b.w;
  #pragma unroll
  for (int off=32; off; off>>=1){ s += __shfl_down(s,off); ss += __shfl_down(ss,off); }
  if (lane==0){
    float mu = s*(1.0f/512.0f);
    float var = ss*(1.0f/512.0f) - mu*mu;
    mu_rstd[tok*2+0] = mu;
    mu_rstd[tok*2+1] = 1.0f/sqrtf(var + 1e-5f);
  }
}

// ----------------------------------- LN + projection GEMM (q, k, v fused-z)
// q/k outputs emitted as bf16 hi/lo split; v output stays fp32 (transposed later)

__global__ __launch_bounds__(256) void k_proj(
    const float* __restrict__ q, const float* __restrict__ k, const float* __restrict__ v,
    const float* __restrict__ g, const float* __restrict__ bln,
    const float* __restrict__ W, const float* __restrict__ mu_rstd,
    unsigned short* __restrict__ fqh, unsigned short* __restrict__ fql,
    unsigned short* __restrict__ fkh, unsigned short* __restrict__ fkl,
    float* __restrict__ fv,
    double* __restrict__ qgs, double* __restrict__ kgs){
  __shared__ float As[64*36];
  __shared__ float Bs[32*68];
  int z = blockIdx.z;
  const float* x = (z==0) ? q : ((z==1) ? k : v);
  int tb = blockIdx.x;         // token tile (64 tokens)
  int hb = blockIdx.y;         // head / 64-col tile
  int tid = threadIdx.x;
  int tx = tid & 15, ty = tid >> 4;
  float acc[4][4] = {};
  for (int kc = 0; kc < 16; ++kc){
    #pragma unroll
    for (int i = 0; i < 2; ++i){
      int idx4 = tid + 256*i;               // 0..511
      int r = idx4 >> 3, k4 = idx4 & 7;
      int tokg = z*4096 + tb*64 + r;
      float mu = mu_rstd[tokg*2+0], rstd = mu_rstd[tokg*2+1];
      float4 xv = *(const float4*)(x + (size_t)(tb*64+r)*DIMX + kc*32 + k4*4);
      float4 gv = *(const float4*)(g   + kc*32 + k4*4);
      float4 bv = *(const float4*)(bln + kc*32 + k4*4);
      float4 yv;
      yv.x = (xv.x-mu)*rstd*gv.x + bv.x;
      yv.y = (xv.y-mu)*rstd*gv.y + bv.y;
      yv.z = (xv.z-mu)*rstd*gv.z + bv.z;
      yv.w = (xv.w-mu)*rstd*gv.w + bv.w;
      *(float4*)(As + r*36 + k4*4) = yv;
    }
    #pragma unroll
    for (int i = 0; i < 2; ++i){
      int idx4 = tid + 256*i;
      int kr = idx4 >> 4, c4 = idx4 & 15;
      *(float4*)(Bs + kr*68 + c4*4) =
          *(const float4*)(W + (size_t)(kc*32+kr)*DIMX + hb*64 + c4*4);
    }
    __syncthreads();
    gemm_micro32(As, Bs, tx, ty, acc);
    __syncthreads();
  }
  if (z == 2){
    #pragma unroll
    for (int i = 0; i < 4; ++i){
      int t = tb*64 + ty*4 + i;
      int qb = t >> 10, n = t & 1023;
      int pp = hb*4 + qb;
      *(float4*)(fv + (size_t)(pp*NTOK + n)*DH + tx*4) =
          make_float4(acc[i][0], acc[i][1], acc[i][2], acc[i][3]);
    }
  } else {
    unsigned short* hd = (z==0) ? fqh : fkh;
    unsigned short* ld = (z==0) ? fql : fkl;
    #pragma unroll
    for (int i = 0; i < 4; ++i){
      int t = tb*64 + ty*4 + i;
      int qb = t >> 10, n = t & 1023;
      int pp = hb*4 + qb;
      size_t base = (size_t)(pp*NTOK + n)*DH + tx*4;
      ushort4 hv, lv;
      { float xx=acc[i][0]; unsigned short hh=f2bf(xx); hv.x=hh; lv.x=f2bf(xx-bf2f(hh)); }
      { float xx=acc[i][1]; unsigned short hh=f2bf(xx); hv.y=hh; lv.y=f2bf(xx-bf2f(hh)); }
      { float xx=acc[i][2]; unsigned short hh=f2bf(xx); hv.z=hh; lv.z=f2bf(xx-bf2f(hh)); }
      { float xx=acc[i][3]; unsigned short hh=f2bf(xx); hv.w=hh; lv.w=f2bf(xx-bf2f(hh)); }
      *(ushort4*)(hd+base) = hv;
      *(ushort4*)(ld+base) = lv;
    }
  }
  if (z < 2){
    __syncthreads();
    float* scr = As;   // 64 cols x 16 ty
    #pragma unroll
    for (int j = 0; j < 4; ++j){
      float cs = acc[0][j]+acc[1][j]+acc[2][j]+acc[3][j];
      scr[(tx*4+j)*16 + ty] = cs;
    }
    __syncthreads();
    if (tid < 64){
      float tot = 0.f;
      #pragma unroll
      for (int e = 0; e < 16; ++e) tot += scr[tid*16+e];
      double* dst = (z==0) ? qgs : kgs;
      atomicAdd(&dst[hb*64 + tid], (double)tot);
    }
  }
}

// ------------------------------------ transpose fv -> fvT (bf16 hi/lo, [p][d][m])

__global__ __launch_bounds__(256) void k_vT(const float* __restrict__ fv,
    unsigned short* __restrict__ fvTh, unsigned short* __restrict__ fvTl){
  __shared__ float tile[64][65];
  int mc = blockIdx.x, p = blockIdx.y, tid = threadIdx.x;
  #pragma unroll
  for (int it=0; it<4; ++it){
    int idx = tid + 256*it;
    int m = idx>>4, d4 = idx&15;
    float4 vv = *(const float4*)(fv + ((size_t)(p*NTOK + mc*64 + m)*DH + d4*4));
    tile[d4*4+0][m]=vv.x; tile[d4*4+1][m]=vv.y; tile[d4*4+2][m]=vv.z; tile[d4*4+3][m]=vv.w;
  }
  __syncthreads();
  #pragma unroll
  for (int it=0; it<2; ++it){
    int idx = tid + 256*it;       // 0..511
    int d = idx>>3, seg = idx&7;  // 8 m per thread
    size_t base = (size_t)(p*DH + d)*NTOK + mc*64 + seg*8;
    ushort4 h0,h1,l0,l1;
    { float xx=tile[d][seg*8+0]; unsigned short hh=f2bf(xx); h0.x=hh; l0.x=f2bf(xx-bf2f(hh)); }
    { float xx=tile[d][seg*8+1]; unsigned short hh=f2bf(xx); h0.y=hh; l0.y=f2bf(xx-bf2f(hh)); }
    { float xx=tile[d][seg*8+2]; unsigned short hh=f2bf(xx); h0.z=hh; l0.z=f2bf(xx-bf2f(hh)); }
    { float xx=tile[d][seg*8+3]; unsigned short hh=f2bf(xx); h0.w=hh; l0.w=f2bf(xx-bf2f(hh)); }
    { float xx=tile[d][seg*8+4]; unsigned short hh=f2bf(xx); h1.x=hh; l1.x=f2bf(xx-bf2f(hh)); }
    { float xx=tile[d][seg*8+5]; unsigned short hh=f2bf(xx); h1.y=hh; l1.y=f2bf(xx-bf2f(hh)); }
    { float xx=tile[d][seg*8+6]; unsigned short hh=f2bf(xx); h1.z=hh; l1.z=f2bf(xx-bf2f(hh)); }
    { float xx=tile[d][seg*8+7]; unsigned short hh=f2bf(xx); h1.w=hh; l1.w=f2bf(xx-bf2f(hh)); }
    *(ushort4*)(fvTh+base)   = h0;
    *(ushort4*)(fvTh+base+4) = h1;
    *(ushort4*)(fvTl+base)   = l0;
    *(ushort4*)(fvTl+base+4) = l1;
  }
}

// -------------------------------------------- nu (col-means of f_k) and S

__global__ __launch_bounds__(256) void k_nu(const unsigned short* __restrict__ fkh,
    const unsigned short* __restrict__ fkl,
    float* __restrict__ nuA, float* __restrict__ Sarr){
  __shared__ float red[4][64];
  int p = blockIdx.x, tid = threadIdx.x;
  int td = tid & 63, tm = tid >> 6;
  float s = 0.f;
  for (int m = tm; m < NTOK; m += 4){
    size_t ix = (size_t)(p*NTOK+m)*DH + td;
    s += bf2f(fkh[ix]) + bf2f(fkl[ix]);
  }
  red[tm][td] = s;
  __syncthreads();
  if (tid < 64){
    float tot = red[0][tid]+red[1][tid]+red[2][tid]+red[3][tid];
    float nuv = tot * (1.0f/1024.0f);
    nuA[p*DH+tid] = nuv;
    float sv = nuv;
    #pragma unroll
    for (int off=32; off; off>>=1) sv += __shfl_down(sv, off);
    if (tid==0) Sarr[p] = sv;
  }
}

// --------------------------------------- per-row scalars for f_q and f_k

__global__ __launch_bounds__(256) void k_rows(
    const unsigned short* __restrict__ fqh, const unsigned short* __restrict__ fql,
    const unsigned short* __restrict__ fkh, const unsigned short* __restrict__ fkl,
    const float* __restrict__ nuA,
    float* __restrict__ inv_na_q, float* __restrict__ inv_nb_q,
    float* __restrict__ muqA, float* __restrict__ tqA,
    float* __restrict__ inv_na_k, float* __restrict__ inv_nb_k,
    float* __restrict__ skA){
  int wid = threadIdx.x >> 6, lane = threadIdx.x & 63;
  int row = blockIdx.x*4 + wid;            // < 32768
  int p = row >> 10;
  size_t ix = (size_t)row*DH + lane;
  float xq = bf2f(fqh[ix]) + bf2f(fql[ix]);
  float nv = nuA[p*DH + lane];
  float s = xq, ss = xq*xq, sd = xq*nv;
  #pragma unroll
  for (int off=32; off; off>>=1){
    s += __shfl_down(s,off); ss += __shfl_down(ss,off); sd += __shfl_down(sd,off);
  }
  if (lane==0){
    float nrm = sqrtf(ss);
    inv_na_q[row] = 1.0f/(nrm+1e-8f);
    inv_nb_q[row] = 1.0f/fmaxf(nrm,1e-6f);
    muqA[row] = s*(1.0f/64.0f);
    tqA[row] = sd;
  }
  float xk = bf2f(fkh[ix]) + bf2f(fkl[ix]);
  float s2 = xk, ss2 = xk*xk;
  #pragma unroll
  for (int off=32; off; off>>=1){
    s2 += __shfl_down(s2,off); ss2 += __shfl_down(ss2,off);
  }
  if (lane==0){
    float nrm = sqrtf(ss2);
    inv_na_k[row] = 1.0f/(nrm+1e-8f);
    inv_nb_k[row] = 1.0f/fmaxf(nrm,1e-6f);
    skA[row] = s2;
  }
}

// ------------------------------------------------- weight predictor (tiny)

__global__ __launch_bounds__(256) void k_wp(const double* __restrict__ qgs,
    const double* __restrict__ kgs,
    const float* __restrict__ W1, const float* __restrict__ b1,
    const float* __restrict__ lgv, const float* __restrict__ lbv,
    const float* __restrict__ W2, const float* __restrict__ b2,
    const float* __restrict__ W3, const float* __restrict__ b3,
    const float* __restrict__ wtemp, float* __restrict__ wp_out){
  __shared__ float feats[8][128];
  __shared__ float h1[8][64];
  __shared__ float h2s[8][32];
  __shared__ float lgt[8][3];
  __shared__ float mv[8][2];
  int tid = threadIdx.x;
  for (int idx = tid; idx < 1024; idx += 256){
    int h = idx >> 7, i = idx & 127;
    double vv = (i < 64) ? qgs[h*64+i] : kgs[h*64+(i-64)];
    feats[h][i] = (float)(vv * (1.0/4096.0));
  }
  __syncthreads();
  for (int idx = tid; idx < 512; idx += 256){
    int h = idx >> 6, j = idx & 63;
    float s = b1[j];
    for (int i = 0; i < 128; ++i) s += feats[h][i]*W1[i*64+j];
    h1[h][j] = s;
  }
  __syncthreads();
  if (tid < 8){
    float s=0.f, ss=0.f;
    for (int j=0;j<64;++j){ float vv=h1[tid][j]; s+=vv; ss+=vv*vv; }
    float mu = s*(1.0f/64.0f);
    float var = ss*(1.0f/64.0f)-mu*mu;
    mv[tid][0]=mu; mv[tid][1]=1.0f/sqrtf(var+1e-5f);
  }
  __syncthreads();
  for (int idx = tid; idx < 512; idx += 256){
    int h = idx>>6, j = idx&63;
    float vv = (h1[h][j]-mv[h][0])*mv[h][1]*lgv[j] + lbv[j];
    h1[h][j] = fmaxf(vv, 0.f);
  }
  __syncthreads();
  {
    int h = tid >> 5, j = tid & 31;
    float s = b2[j];
    for (int i=0;i<64;++i) s += h1[h][i]*W2[i*32+j];
    h2s[h][j] = fmaxf(s, 0.f);
  }
  __syncthreads();
  if (tid < 24){
    int h = tid/3, j = tid - h*3;
    float s = b3[j];
    for (int i=0;i<32;++i) s += h2s[h][i]*W3[i*3+j];
    lgt[h][j] = s;
  }
  __syncthreads();
  if (tid < 8){
    int h = tid;
    float z0=lgt[h][0], z1=lgt[h][1], z2=lgt[h][2];
    float m = fmaxf(z0,fmaxf(z1,z2));
    float e0=expf(z0-m), e1=expf(z1-m), e2=expf(z2-m);
    float inv = 1.0f/(e0+e1+e2);
    float l0=e0*inv, l1=e1*inv, l2=e2*inv;
    float wt = fminf(fmaxf(wtemp[0], 0.1f), 20.0f);
    float y0=l0/wt, y1=l1/wt, y2=l2/wt;
    float m2 = fmaxf(y0,fmaxf(y1,y2));
    float f0=expf(y0-m2), f1=expf(y1-m2), f2=expf(y2-m2);
    float inv2 = 1.0f/(f0+f1+f2);
    float w0=f0*inv2, w1=f1*inv2, w2=f2*inv2;
    w0 = fminf(fmaxf(w0,0.05f),0.8f);
    w1 = fminf(fmaxf(w1,0.05f),0.8f);
    w2 = fminf(fmaxf(w2,0.05f),0.8f);
    float isum = 1.0f/(w0+w1+w2);
    wp_out[h*3+0]=w0*isum; wp_out[h*3+1]=w1*isum; wp_out[h*3+2]=w2*isum;
  }
}

// ------------------------- pass A (MFMA): QK^T, derive cos/cov/margin, stats

__global__ __launch_bounds__(256) void k_passA(
    const unsigned short* __restrict__ fqh, const unsigned short* __restrict__ fql,
    const unsigned short* __restrict__ fkh, const unsigned short* __restrict__ fkl,
    const float* __restrict__ inv_na_q, const float* __restrict__ inv_nb_q,
    const float* __restrict__ muqA, const float* __restrict__ tqA,
    const float* __restrict__ inv_na_k, const float* __restrict__ inv_nb_k,
    const float* __restrict__ skA, const float* __restrict__ Sarr,
    float* __restrict__ rs_cos, float* __restrict__ rs_cov, float* __restrict__ rs_marg,
    float* __restrict__ mxcosA, float* __restrict__ mncosA,
    float* __restrict__ mxcovA, float* __restrict__ mncovA,
    double* __restrict__ gacc){
  __shared__ float cAs[1024], cBs[1024], cSs[1024];
  __shared__ float redbuf[4][16][8];
  __shared__ double wredS[4][5];
  int b = blockIdx.x, p = b>>5, s = b&31, n0 = s*32;
  int tid = threadIdx.x, w = tid>>6, l = tid&63;
  int rt = w&1, cw = w>>1, lm = l&15, q = l>>4;
  for (int idx = tid; idx < 1024; idx += 256){
    int rg = p*NTOK + idx;
    cAs[idx] = inv_na_k[rg]; cBs[idx] = inv_nb_k[rg]; cSs[idx] = skA[rg];
  }
  float Sp = Sarr[p];
  float ia[4], ib[4], mq[4], tq2[4];
  #pragma unroll
  for (int i=0;i<4;++i){
    int rg = p*NTOK + n0 + rt*16 + q*4 + i;
    ia[i]=inv_na_q[rg]; ib[i]=inv_nb_q[rg]; mq[i]=muqA[rg];
    tq2[i]=tqA[rg] - mq[i]*Sp;
  }
  const short8* aqhp = (const short8*)(fqh + (size_t)(p*NTOK + n0 + rt*16 + lm)*DH);
  const short8* aqlp = (const short8*)(fql + (size_t)(p*NTOK + n0 + rt*16 + lm)*DH);
  short8 ah0 = aqhp[q], ah1 = aqhp[4+q], al0 = aqlp[q], al1 = aqlp[4+q];
  __syncthreads();
  const float inv8 = (float)(1.0/(8.0+1e-6));
  double dc1=0,dc2=0,dv1=0,dv2=0,dcv=0;
  float pc[4]={0,0,0,0}, pv_[4]={0,0,0,0}, pm[4]={0,0,0,0};
  float xc[4], nc[4], xv[4], nv[4];
  #pragma unroll
  for (int i=0;i<4;++i){ xc[i]=-1e30f; nc[i]=1e30f; xv[i]=-1e30f; nv[i]=1e30f; }
  for (int t=0; t<32; ++t){
    int c = cw + 2*t;
    const short8* bhp = (const short8*)(fkh + (size_t)(p*NTOK + c*16 + lm)*DH);
    const short8* blp = (const short8*)(fkl + (size_t)(p*NTOK + c*16 + lm)*DH);
    short8 bh0=bhp[q], bh1=bhp[4+q], bl0=blp[q], bl1=blp[4+q];
    f32x4 acc = {0.f,0.f,0.f,0.f};
    acc = mfma16(ah0,bh0,acc); acc = mfma16(ah1,bh1,acc);
    acc = mfma16(al0,bh0,acc); acc = mfma16(al1,bh1,acc);
    acc = mfma16(ah0,bl0,acc); acc = mfma16(ah1,bl1,acc);
    int col = c*16 + lm;
    float ca=cAs[col], cb=cBs[col], cs=cSs[col];
    #pragma unroll
    for (int i=0;i<4;++i){
      float dot = acc[i];
      float cosv = fminf(fmaxf(dot*ia[i]*ca,-0.99f),0.99f);
      float csim = fminf(fmaxf(dot*ib[i]*cb,-0.99f),0.99f);
      float marg = fmaxf(0.01f - csim, 0.f);
      float cov  = (dot - tq2[i] - mq[i]*cs)*inv8;
      double cd=(double)cosv, vd=(double)cov;
      dc1+=cd; dc2=fma(cd,cd,dc2); dv1+=vd; dv2=fma(vd,vd,dv2); dcv=fma(cd,vd,dcv);
      pc[i]+=cosv; pv_[i]+=cov; pm[i]+=marg;
      xc[i]=fmaxf(xc[i],cosv); nc[i]=fminf(nc[i],cosv);
      xv[i]=fmaxf(xv[i],cov);  nv[i]=fminf(nv[i],cov);
    }
  }
  #pragma unroll
  for (int m=1;m<16;m<<=1){
    #pragma unroll
    for (int i=0;i<4;++i){
      pc[i]+=__shfl_xor(pc[i],m); pv_[i]+=__shfl_xor(pv_[i],m); pm[i]+=__shfl_xor(pm[i],m);
      xc[i]=fmaxf(xc[i],__shfl_xor(xc[i],m)); nc[i]=fminf(nc[i],__shfl_xor(nc[i],m));
      xv[i]=fmaxf(xv[i],__shfl_xor(xv[i],m)); nv[i]=fminf(nv[i],__shfl_xor(nv[i],m));
    }
  }
  if (lm==0){
    #pragma unroll
    for (int i=0;i<4;++i){
      int r16 = q*4+i;
      redbuf[w][r16][0]=pc[i]; redbuf[w][r16][1]=pv_[i]; redbuf[w][r16][2]=pm[i];
      redbuf[w][r16][3]=xc[i]; redbuf[w][r16][4]=nc[i];
      redbuf[w][r16][5]=xv[i]; redbuf[w][r16][6]=nv[i];
    }
  }
  double vals[5] = {dc1,dc2,dv1,dv2,dcv};
  #pragma unroll
  for (int c2=0;c2<5;++c2){
    double vv = vals[c2];
    #pragma unroll
    for (int off=32; off; off>>=1) vv += __shfl_down(vv, off);
    if (l==0) wredS[w][c2] = vv;
  }
  __syncthreads();
  if (tid < 32){
    int rt2 = tid>>4, r16 = tid&15;
    int w0 = rt2, w1 = rt2+2;
    float sc = redbuf[w0][r16][0]+redbuf[w1][r16][0];
    float sv = redbuf[w0][r16][1]+redbuf[w1][r16][1];
    float sm = redbuf[w0][r16][2]+redbuf[w1][r16][2];
    float mxc = fmaxf(redbuf[w0][r16][3],redbuf[w1][r16][3]);
    float mnc = fminf(redbuf[w0][r16][4],redbuf[w1][r16][4]);
    float mxv = fmaxf(redbuf[w0][r16][5],redbuf[w1][r16][5]);
    float mnv = fminf(redbuf[w0][r16][6],redbuf[w1][r16][6]);
    int row = p*NTOK + n0 + tid;
    rs_cos[row]=sc; rs_cov[row]=sv; rs_marg[row]=sm;
    mxcosA[row]=mxc; mncosA[row]=mnc; mxcovA[row]=mxv; mncovA[row]=mnv;
  }
  if (tid == 0){
    int h = p >> 2;
    #pragma unroll
    for (int c2=0;c2<5;++c2){
      double t = wredS[0][c2]+wredS[1][c2]+wredS[2][c2]+wredS[3][c2];
      atomicAdd(&gacc[h*5+c2], t);
    }
  }
}

// ---------------------- row finish: var_row + var-related global moments

__global__ __launch_bounds__(256) void k_rowfin(const float* __restrict__ rs_cos,
    const float* __restrict__ rs_cov, const float* __restrict__ rs_marg,
    float* __restrict__ var_row, double* __restrict__ racc){
  __shared__ double wredS[4][4];
  int row = blockIdx.x*256 + threadIdx.x;
  int p = row >> 10; int h = p >> 2;
  float vr = rs_marg[row] * (1.0f/1024.0f);
  var_row[row] = vr;
  double dv = (double)vr;
  double vals[4];
  vals[0] = 1024.0*dv;
  vals[1] = 1024.0*dv*dv;
  vals[2] = dv*(double)rs_cos[row];
  vals[3] = dv*(double)rs_cov[row];
  int lane = threadIdx.x & 63, wid = threadIdx.x >> 6;
  #pragma unroll
  for (int c2 = 0; c2 < 4; ++c2){
    double vv = vals[c2];
    #pragma unroll
    for (int off=32; off; off>>=1) vv += __shfl_down(vv, off);
    if (lane==0) wredS[wid][c2] = vv;
  }
  __syncthreads();
  if (threadIdx.x == 0){
    #pragma unroll
    for (int c2 = 0; c2 < 4; ++c2){
      double t = wredS[0][c2]+wredS[1][c2]+wredS[2][c2]+wredS[3][c2];
      atomicAdd(&racc[h*4+c2], t);
    }
  }
}

// ------------------------------------- finalize scalars -> d2 coefficients

__global__ void k_final(const double* __restrict__ gacc, const double* __restrict__ racc,
                        const float* __restrict__ wp_out, float* __restrict__ coef){
  if (threadIdx.x != 0) return;
  const double N = 33554432.0;
  double Sc1=0,Sc2=0,Sv1=0,Sv2=0,Sr1=0,Sr2=0;
  for (int h=0;h<8;++h){
    Sc1+=gacc[h*5+0]; Sc2+=gacc[h*5+1]; Sv1+=gacc[h*5+2]; Sv2+=gacc[h*5+3];
    Sr1+=racc[h*4+0]; Sr2+=racc[h*4+1];
  }
  double cvar = (Sc2 - Sc1*Sc1/N)/(N-1.0);
  double cn = sqrt(fmax(cvar,0.0)) + 1e-6;
  double cscale = (cn < 1e-4) ? 0.1 : 1.0;
  double vraw = (Sv2 - Sv1*Sv1/N)/(N-1.0);
  double sraw = sqrt(fmax(vraw,0.0));
  double basev = 0.001/1024.0;
  double regv = (sraw < 1e-6) ? basev*10.0 : basev;
  double covn = regv*sraw + 1e-6;
  double vvar = (Sr2 - Sr1*Sr1/N)/(N-1.0);
  double vn = sqrt(fmax(vvar,0.0)) + 1e-6;
  double ah[8], bh[8], chh[8];
  double Sd1=0.0, Sd2=0.0;
  for (int h=0;h<8;++h){
    double a = (double)wp_out[h*3+0]/cn*cscale;
    double b = (double)wp_out[h*3+1]*regv*0.5/covn;
    double c = (double)wp_out[h*3+2]*0.5/vn;
    ah[h]=a; bh[h]=b; chh[h]=c;
    Sd1 += a*gacc[h*5+0] + b*gacc[h*5+2] + c*racc[h*4+0];
    Sd2 += a*a*gacc[h*5+1] + b*b*gacc[h*5+3] + c*c*racc[h*4+1]
         + 2.0*(a*b*gacc[h*5+4] + a*c*racc[h*4+2] + b*c*racc[h*4+3]);
  }
  double dvar = (Sd2 - Sd1*Sd1/N)/(N-1.0);
  double dstd = sqrt(fmax(dvar,0.0));
  double temp = (dstd < 1e-6) ? 0.1 : 0.3 + dstd;
  double tcl = fmin(fmax(temp,0.1),5.0);
  double it = 1.0/tcl;
  for (int h=0;h<8;++h){
    coef[h*3+0] = (float)(ah[h]*it);
    coef[h*3+1] = (float)(bh[h]*it);
    coef[h*3+2] = (float)(chh[h]*it);
  }
}

// -------------------- pass C (MFMA): recompute QK, softmax via bound, PV

__global__ __launch_bounds__(256) void k_pv(
    const unsigned short* __restrict__ fqh, const unsigned short* __restrict__ fql,
    const unsigned short* __restrict__ fkh, const unsigned short* __restrict__ fkl,
    const unsigned short* __restrict__ fvTh, const unsigned short* __restrict__ fvTl,
    const float* __restrict__ inv_na_q, const float* __restrict__ muqA,
    const float* __restrict__ tqA,
    const float* __restrict__ inv_na_k, const float* __restrict__ skA,
    const float* __restrict__ Sarr, const float* __restrict__ var_row,
    const float* __restrict__ mxcosA, const float* __restrict__ mncosA,
    const float* __restrict__ mxcovA, const float* __restrict__ mncovA,
    const float* __restrict__ coef, float* __restrict__ oh){
  __shared__ float cAs[1024], cSs[1024];
  __shared__ __align__(16) unsigned short ph[32][72];
  __shared__ __align__(16) unsigned short pl[32][72];
  __shared__ float denbuf[4][16];
  __shared__ float dnv[32];
  int b = blockIdx.x, p = b>>5, s = b&31, n0 = s*32;
  int h = p>>2, qb = p&3;
  int tid = threadIdx.x, w = tid>>6, l = tid&63;
  int rt = w&1, cw = w>>1, lm = l&15, q = l>>4;
  float A = coef[h*3+0], B = coef[h*3+1], C = coef[h*3+2];
  for (int idx = tid; idx < 1024; idx += 256){
    int rg = p*NTOK + idx;
    cAs[idx] = inv_na_k[rg]; cSs[idx] = skA[rg];
  }
  float Sp = Sarr[p];
  float ia[4], mq[4], tq2[4], off[4];
  #pragma unroll
  for (int i=0;i<4;++i){
    int rg = p*NTOK + n0 + rt*16 + q*4 + i;
    ia[i]=inv_na_q[rg]; mq[i]=muqA[rg];
    tq2[i]=tqA[rg] - mq[i]*Sp;
    float vr = var_row[rg];
    float Mh = fmaxf(A*mxcosA[rg],A*mncosA[rg]) + fmaxf(B*mxcovA[rg],B*mncovA[rg]) + C*vr;
    off[i] = C*vr - Mh;
  }
  const short8* aqhp = (const short8*)(fqh + (size_t)(p*NTOK + n0 + rt*16 + lm)*DH);
  const short8* aqlp = (const short8*)(fql + (size_t)(p*NTOK + n0 + rt*16 + lm)*DH);
  short8 ah0 = aqhp[q], ah1 = aqhp[4+q], al0 = aqlp[q], al1 = aqlp[4+q];
  const float inv8 = (float)(1.0/(8.0+1e-6));
  f32x4 o0 = {0.f,0.f,0.f,0.f}, o1 = {0.f,0.f,0.f,0.f};
  float den[4] = {0.f,0.f,0.f,0.f};
  __syncthreads();
  for (int cc = 0; cc < 16; ++cc){
    int m0 = cc*64;
    #pragma unroll
    for (int t2=0;t2<2;++t2){
      int c16 = cw*2 + t2;
      int colg = m0 + c16*16 + lm;
      const short8* bhp = (const short8*)(fkh + (size_t)(p*NTOK + colg)*DH);
      const short8* blp = (const short8*)(fkl + (size_t)(p*NTOK + colg)*DH);
      short8 bh0=bhp[q], bh1=bhp[4+q], bl0=blp[q], bl1=blp[4+q];
      f32x4 acc = {0.f,0.f,0.f,0.f};
      acc = mfma16(ah0,bh0,acc); acc = mfma16(ah1,bh1,acc);
      acc = mfma16(al0,bh0,acc); acc = mfma16(al1,bh1,acc);
      acc = mfma16(ah0,bl0,acc); acc = mfma16(ah1,bl1,acc);
      float ca = cAs[colg], cs = cSs[colg];
      #pragma unroll
      for (int i=0;i<4;++i){
        float dot = acc[i];
        float cosv = fminf(fmaxf(dot*ia[i]*ca,-0.99f),0.99f);
        float cov  = (dot - tq2[i] - mq[i]*cs)*inv8;
        float e = __expf(A*cosv + B*cov + off[i]);
        den[i] += e;
        unsigned short hi = f2bf(e);
        unsigned short lo = f2bf(e - bf2f(hi));
        ph[rt*16+q*4+i][c16*16+lm] = hi;
        pl[rt*16+q*4+i][c16*16+lm] = lo;
      }
    }
    __syncthreads();
    const short8* avh = (const short8*)(fvTh + ((size_t)(p*DH + w*16 + lm)*NTOK + m0));
    const short8* avl = (const short8*)(fvTl + ((size_t)(p*DH + w*16 + lm)*NTOK + m0));
    #pragma unroll
    for (int kk=0;kk<2;++kk){
      short8 ahv = avh[kk*4+q], alv = avl[kk*4+q];
      short8 b0h = *(const short8*)(&ph[lm][kk*32+q*8]);
      short8 b0l = *(const short8*)(&pl[lm][kk*32+q*8]);
      short8 b1h = *(const short8*)(&ph[16+lm][kk*32+q*8]);
      short8 b1l = *(const short8*)(&pl[16+lm][kk*32+q*8]);
      o0 = mfma16(ahv,b0h,o0); o0 = mfma16(ahv,b0l,o0); o0 = mfma16(alv,b0h,o0);
      o1 = mfma16(ahv,b1h,o1); o1 = mfma16(ahv,b1l,o1); o1 = mfma16(alv,b1h,o1);
    }
    __syncthreads();
  }
  #pragma unroll
  for (int m=1;m<16;m<<=1){
    #pragma unroll
    for (int i=0;i<4;++i) den[i] += __shfl_xor(den[i],m);
  }
  if (lm==0){
    #pragma unroll
    for (int i=0;i<4;++i) denbuf[w][q*4+i] = den[i];
  }
  __syncthreads();
  if (tid < 32){
    int rt2 = tid>>4, r16 = tid&15;
    dnv[tid] = 1.0f/(denbuf[rt2][r16] + denbuf[rt2+2][r16]);
  }
  __syncthreads();
  {
    float inv0 = dnv[lm];
    float inv1 = dnv[16+lm];
    int d0 = w*16 + q*4;
    float4 s0 = make_float4(o0[0]*inv0, o0[1]*inv0, o0[2]*inv0, o0[3]*inv0);
    float4 s1 = make_float4(o1[0]*inv1, o1[1]*inv1, o1[2]*inv1, o1[3]*inv1);
    *(float4*)(oh + ((size_t)(qb*NTOK + n0 + lm)*NH + h)*DH + d0) = s0;
    *(float4*)(oh + ((size_t)(qb*NTOK + n0 + 16 + lm)*NH + h)*DH + d0) = s1;
  }
}

// ------------------------------------------- output GEMM: oh @ W_out + b

__global__ __launch_bounds__(256) void k_out(const float* __restrict__ Ain,
    const float* __restrict__ W, const float* __restrict__ bias,
    float* __restrict__ out){
  __shared__ float As[64*36];
  __shared__ float Bs[32*68];
  int tb = blockIdx.x, cb = blockIdx.y;
  int tid = threadIdx.x;
  int tx = tid & 15, ty = tid >> 4;
  float acc[4][4] = {};
  for (int kc = 0; kc < 16; ++kc){
    #pragma unroll
    for (int i = 0; i < 2; ++i){
      int idx4 = tid + 256*i;
      int r = idx4 >> 3, k4 = idx4 & 7;
      *(float4*)(As + r*36 + k4*4) =
          *(const float4*)(Ain + (size_t)(tb*64+r)*DIMX + kc*32 + k4*4);
    }
    #pragma unroll
    for (int i = 0; i < 2; ++i){
      int idx4 = tid + 256*i;
      int kr = idx4 >> 4, c4 = idx4 & 15;
      *(float4*)(Bs + kr*68 + c4*4) =
          *(const float4*)(W + (size_t)(kc*32+kr)*DIMX + cb*64 + c4*4);
    }
    __syncthreads();
    gemm_micro32(As, Bs, tx, ty, acc);
    __syncthreads();
  }
  float4 bv = *(const float4*)(bias + cb*64 + tx*4);
  #pragma unroll
  for (int i = 0; i < 4; ++i){
    int t = tb*64 + ty*4 + i;
    float4 o = make_float4(acc[i][0]+bv.x, acc[i][1]+bv.y, acc[i][2]+bv.z, acc[i][3]+bv.w);
    *(float4*)(out + (size_t)t*DIMX + cb*64 + tx*4) = o;
  }
}

// ----------------------------------------------------------------- launch

extern "C" void kernel_launch(void* const* d_in, const int* in_sizes, int n_in,
                              void* d_out, int out_size, void* d_ws, size_t ws_size,
                              hipStream_t stream) {
  (void)in_sizes; (void)n_in; (void)out_size;
  const float* q     = (const float*)d_in[0];
  const float* k     = (const float*)d_in[1];
  const float* v     = (const float*)d_in[2];
  const float* ln_g  = (const float*)d_in[3];
  const float* ln_b  = (const float*)d_in[4];
  const float* W_in  = (const float*)d_in[5];
  const float* wp_W1 = (const float*)d_in[6];
  const float* wp_b1 = (const float*)d_in[7];
  const float* wp_lg = (const float*)d_in[8];
  const float* wp_lb = (const float*)d_in[9];
  const float* wp_W2 = (const float*)d_in[10];
  const float* wp_b2 = (const float*)d_in[11];
  const float* wp_W3 = (const float*)d_in[12];
  const float* wp_b3 = (const float*)d_in[13];
  const float* wtemp = (const float*)d_in[14];
  const float* W_out = (const float*)d_in[15];
  const float* b_out = (const float*)d_in[16];
  float* out = (float*)d_out;

  char* wsb = (char*)d_ws;
  double* gacc = (double*)wsb;            // 40 doubles
  double* racc = gacc + 40;               // 32
  double* qgs  = racc + 32;               // 512
  double* kgs  = qgs + 512;               // 512  (zone0 total 8768 B < 16384)
  float* fvA = (float*)(wsb + 16384);     // 2M floats (8 MB); reused as oh after k_vT
  float* oh  = fvA;
  float* mu_rstd = fvA + (size_t)NPAIR*NTOK*DH;   // 24576
  float* nuA  = mu_rstd + 24576;          // 2048
  float* Sarr = nuA + 2048;               // 64 (padded)
  float* inv_na_q = Sarr + 64;
  float* inv_nb_q = inv_na_q + NROWS;
  float* muqA     = inv_nb_q + NROWS;
  float* tqA      = muqA + NROWS;
  float* inv_na_k = tqA + NROWS;
  float* inv_nb_k = inv_na_k + NROWS;
  float* skA      = inv_nb_k + NROWS;
  float* rs_cos   = skA + NROWS;
  float* rs_cov   = rs_cos + NROWS;
  float* rs_marg  = rs_cov + NROWS;
  float* var_row  = rs_marg + NROWS;
  float* mxcos    = var_row + NROWS;
  float* mncos    = mxcos + NROWS;
  float* mxcov    = mncos + NROWS;
  float* mncov    = mxcov + NROWS;
  float* wp_out   = mncov + NROWS;        // 32 (padded)
  float* coef     = wp_out + 32;          // 32 (padded)
  float* endf     = coef + 32;
  size_t off16 = (size_t)((char*)endf - wsb);
  off16 = (off16 + 63) & ~(size_t)63;
  unsigned short* fqh  = (unsigned short*)(wsb + off16);
  unsigned short* fql  = fqh  + (size_t)NPAIR*NTOK*DH;
  unsigned short* fkh  = fql  + (size_t)NPAIR*NTOK*DH;
  unsigned short* fkl  = fkh  + (size_t)NPAIR*NTOK*DH;
  unsigned short* fvTh = fkl  + (size_t)NPAIR*NTOK*DH;
  unsigned short* fvTl = fvTh + (size_t)NPAIR*NTOK*DH;
  size_t need = (size_t)((char*)(fvTl + (size_t)NPAIR*NTOK*DH) - wsb);
  if (ws_size < need) return;  // fail cleanly rather than corrupt

  hipMemsetAsync(wsb, 0, 16384, stream);
  k_lnstats<<<3072, 256, 0, stream>>>(q, k, v, mu_rstd);
  k_proj<<<dim3(64,8,3), 256, 0, stream>>>(q, k, v, ln_g, ln_b, W_in, mu_rstd,
                                           fqh, fql, fkh, fkl, fvA, qgs, kgs);
  k_vT<<<dim3(16,32), 256, 0, stream>>>(fvA, fvTh, fvTl);
  k_nu<<<32, 256, 0, stream>>>(fkh, fkl, nuA, Sarr);
  k_rows<<<8192, 256, 0, stream>>>(fqh, fql, fkh, fkl, nuA,
                                   inv_na_q, inv_nb_q, muqA, tqA,
                                   inv_na_k, inv_nb_k, skA);
  k_wp<<<1, 256, 0, stream>>>(qgs, kgs, wp_W1, wp_b1, wp_lg, wp_lb,
                              wp_W2, wp_b2, wp_W3, wp_b3, wtemp, wp_out);
  k_passA<<<1024, 256, 0, stream>>>(fqh, fql, fkh, fkl,
                                    inv_na_q, inv_nb_q, muqA, tqA,
                                    inv_na_k, inv_nb_k, skA, Sarr,
                                    rs_cos, rs_cov, rs_marg,
                                    mxcos, mncos, mxcov, mncov, gacc);
  k_rowfin<<<128, 256, 0, stream>>>(rs_cos, rs_cov, rs_marg, var_row, racc);
  k_final<<<1, 64, 0, stream>>>(gacc, racc, wp_out, coef);
  k_pv<<<1024, 256, 0, stream>>>(fqh, fql, fkh, fkl, fvTh, fvTl,
                                 inv_na_q, muqA, tqA, inv_na_k, skA, Sarr,
                                 var_row, mxcos, mncos, mxcov, mncov, coef, oh);
  k_out<<<dim3(64,8), 256, 0, stream>>>(oh, W_out, b_out, out);
}

// Round 3
// 488.770 us; speedup vs baseline: 1.5134x; 1.1289x over previous
//
#include <hip/hip_runtime.h>
#include <math.h>

#define NH    8
#define NQB   4
#define NPAIR 32
#define NTOK  1024
#define DH    64
#define DIMX  512
#define NROWS (NPAIR*NTOK)

typedef __attribute__((ext_vector_type(8))) short short8;
typedef __attribute__((ext_vector_type(4))) float f32x4;

__device__ __forceinline__ unsigned short f2bf(float x){
  unsigned u = __float_as_uint(x);
  u += 0x7fffu + ((u>>16)&1u);
  return (unsigned short)(u>>16);
}
__device__ __forceinline__ float bf2f(unsigned short h){
  return __uint_as_float(((unsigned)h)<<16);
}
__device__ __forceinline__ f32x4 mfma16(short8 a, short8 b, f32x4 c){
  return __builtin_amdgcn_mfma_f32_16x16x32_bf16(a,b,c,0,0,0);
}

// ------------------------------------------------- per-token LN statistics

__global__ __launch_bounds__(256) void k_lnstats(const float* __restrict__ q,
    const float* __restrict__ k, const float* __restrict__ v,
    float* __restrict__ mu_rstd){
  int wid = threadIdx.x >> 6, lane = threadIdx.x & 63;
  int tok = blockIdx.x*4 + wid;            // 0..12287
  const float* src = (tok < 4096) ? q : ((tok < 8192) ? k : v);
  int t = tok & 4095;
  const float4* p4 = (const float4*)(src + (size_t)t*DIMX) + lane*2;
  float4 a = p4[0], b = p4[1];
  float s  = a.x+a.y+a.z+a.w + b.x+b.y+b.z+b.w;
  float ss = a.x*a.x+a.y*a.y+a.z*a.z+a.w*a.w
           + b.x*b.x+b.y*b.y+b.z*b.z+b.w*b.w;
  #pragma unroll
  for (int off=32; off; off>>=1){ s += __shfl_down(s,off); ss += __shfl_down(ss,off); }
  if (lane==0){
    float mu = s*(1.0f/512.0f);
    float var = ss*(1.0f/512.0f) - mu*mu;
    mu_rstd[tok*2+0] = mu;
    mu_rstd[tok*2+1] = 1.0f/sqrtf(var + 1e-5f);
  }
}

// ---------------- transpose + hi/lo split of W_in and W_out -> [n][k] bf16

__global__ __launch_bounds__(256) void k_splitW(const float* __restrict__ Wa,
    const float* __restrict__ Wb,
    unsigned short* __restrict__ Wth, unsigned short* __restrict__ Wtl,
    unsigned short* __restrict__ Woth, unsigned short* __restrict__ Wotl){
  __shared__ float tile[64][65];
  int z = blockIdx.z;
  const float* W = z ? Wb : Wa;
  unsigned short* oh_ = z ? Woth : Wth;
  unsigned short* ol_ = z ? Wotl : Wtl;
  int kb = blockIdx.x, nb = blockIdx.y, tid = threadIdx.x;
  #pragma unroll
  for (int it=0; it<4; ++it){
    int idx = tid + 256*it;          // 0..1023
    int kr = idx>>4, c4 = idx&15;
    float4 vv = *(const float4*)(W + (size_t)(kb*64+kr)*DIMX + nb*64 + c4*4);
    tile[c4*4+0][kr]=vv.x; tile[c4*4+1][kr]=vv.y; tile[c4*4+2][kr]=vv.z; tile[c4*4+3][kr]=vv.w;
  }
  __syncthreads();
  #pragma unroll
  for (int it=0; it<4; ++it){
    int idx = tid + 256*it;
    int n = idx>>4, k4 = idx&15;
    size_t base = (size_t)(nb*64+n)*DIMX + kb*64 + k4*4;
    ushort4 hv, lv;
    { float xx=tile[n][k4*4+0]; unsigned short hh=f2bf(xx); hv.x=hh; lv.x=f2bf(xx-bf2f(hh)); }
    { float xx=tile[n][k4*4+1]; unsigned short hh=f2bf(xx); hv.y=hh; lv.y=f2bf(xx-bf2f(hh)); }
    { float xx=tile[n][k4*4+2]; unsigned short hh=f2bf(xx); hv.z=hh; lv.z=f2bf(xx-bf2f(hh)); }
    { float xx=tile[n][k4*4+3]; unsigned short hh=f2bf(xx); hv.w=hh; lv.w=f2bf(xx-bf2f(hh)); }
    *(ushort4*)(oh_+base) = hv;
    *(ushort4*)(ol_+base) = lv;
  }
}

// --------------- LN + projection GEMM via split-bf16 MFMA (q, k, v by z)

__global__ __launch_bounds__(256) void k_projmm(
    const float* __restrict__ q, const float* __restrict__ k, const float* __restrict__ v,
    const float* __restrict__ g, const float* __restrict__ bln,
    const unsigned short* __restrict__ Wth, const unsigned short* __restrict__ Wtl,
    const float* __restrict__ mu_rstd,
    unsigned short* __restrict__ fqh, unsigned short* __restrict__ fql,
    unsigned short* __restrict__ fkh, unsigned short* __restrict__ fkl,
    float* __restrict__ fv,
    double* __restrict__ qgs, double* __restrict__ kgs){
  __shared__ __align__(16) unsigned short Ahs[64*72];
  __shared__ __align__(16) unsigned short Als[64*72];
  __shared__ float scrc[4][128];
  int z = blockIdx.z;
  const float* x = (z==0) ? q : ((z==1) ? k : v);
  int mb = blockIdx.x, nb = blockIdx.y;
  int tid = threadIdx.x, w = tid>>6, l = tid&63, lm = l&15, qd = l>>4;
  int rbase = (w&1)*32;
  int cbase = nb*128 + (w>>1)*64;
  scrc[tid>>7][tid&127] = 0.f;
  scrc[2+(tid>>7)][tid&127] = 0.f;
  f32x4 acc[2][4];
  #pragma unroll
  for (int mt=0;mt<2;++mt)
    #pragma unroll
    for (int nt=0;nt<4;++nt) acc[mt][nt] = (f32x4){0.f,0.f,0.f,0.f};
  for (int kc8 = 0; kc8 < 8; ++kc8){
    // stage 64 rows x 64 k, LN'd, split hi/lo
    float4 xv[4]; float mus[4], rss[4]; float4 gv[4], bv[4]; int rr[4], kk4[4];
    #pragma unroll
    for (int it=0; it<4; ++it){
      int idx = tid + 256*it;          // 0..1023
      int r = idx>>4, k4 = idx&15;
      rr[it]=r; kk4[it]=k4;
      int tokg = z*4096 + mb*64 + r;
      mus[it] = mu_rstd[tokg*2+0]; rss[it] = mu_rstd[tokg*2+1];
      xv[it] = *(const float4*)(x + (size_t)(mb*64+r)*DIMX + kc8*64 + k4*4);
      gv[it] = *(const float4*)(g   + kc8*64 + k4*4);
      bv[it] = *(const float4*)(bln + kc8*64 + k4*4);
    }
    __syncthreads();   // previous iteration's reads complete
    #pragma unroll
    for (int it=0; it<4; ++it){
      float y0 = (xv[it].x-mus[it])*rss[it]*gv[it].x + bv[it].x;
      float y1 = (xv[it].y-mus[it])*rss[it]*gv[it].y + bv[it].y;
      float y2 = (xv[it].z-mus[it])*rss[it]*gv[it].z + bv[it].z;
      float y3 = (xv[it].w-mus[it])*rss[it]*gv[it].w + bv[it].w;
      ushort4 hv, lv;
      { unsigned short hh=f2bf(y0); hv.x=hh; lv.x=f2bf(y0-bf2f(hh)); }
      { unsigned short hh=f2bf(y1); hv.y=hh; lv.y=f2bf(y1-bf2f(hh)); }
      { unsigned short hh=f2bf(y2); hv.z=hh; lv.z=f2bf(y2-bf2f(hh)); }
      { unsigned short hh=f2bf(y3); hv.w=hh; lv.w=f2bf(y3-bf2f(hh)); }
      *(ushort4*)(Ahs + rr[it]*72 + kk4[it]*4) = hv;
      *(ushort4*)(Als + rr[it]*72 + kk4[it]*4) = lv;
    }
    __syncthreads();
    #pragma unroll
    for (int kch=0; kch<2; ++kch){
      short8 a_h[2], a_l[2];
      #pragma unroll
      for (int mt=0;mt<2;++mt){
        a_h[mt] = *(const short8*)(Ahs + (rbase+mt*16+lm)*72 + kch*32 + qd*8);
        a_l[mt] = *(const short8*)(Als + (rbase+mt*16+lm)*72 + kch*32 + qd*8);
      }
      #pragma unroll
      for (int nt=0;nt<4;++nt){
        int cg = cbase + nt*16 + lm;
        size_t wix = (size_t)cg*DIMX + kc8*64 + kch*32 + qd*8;
        short8 bh = *(const short8*)(Wth + wix);
        short8 bl = *(const short8*)(Wtl + wix);
        #pragma unroll
        for (int mt=0;mt<2;++mt){
          acc[mt][nt] = mfma16(a_h[mt], bh, acc[mt][nt]);
          acc[mt][nt] = mfma16(a_h[mt], bl, acc[mt][nt]);
          acc[mt][nt] = mfma16(a_l[mt], bh, acc[mt][nt]);
        }
      }
    }
  }
  // epilogue
  int head = cbase >> 6;               // = nb*2 + (w>>1)
  if (z < 2){
    unsigned short* hd = (z==0) ? fqh : fkh;
    unsigned short* ld_ = (z==0) ? fql : fkl;
    float csum[4] = {0.f,0.f,0.f,0.f};
    #pragma unroll
    for (int mt=0;mt<2;++mt){
      #pragma unroll
      for (int nt=0;nt<4;++nt){
        #pragma unroll
        for (int i=0;i<4;++i){
          float val = acc[mt][nt][i];
          csum[nt] += val;
          int tglob = mb*64 + rbase + mt*16 + qd*4 + i;
          int qb = tglob>>10, n = tglob&1023;
          int p = head*4 + qb;
          int d = nt*16 + lm;
          size_t ix = ((size_t)(p*NTOK+n))*DH + d;
          unsigned short hh = f2bf(val);
          hd[ix] = hh; ld_[ix] = f2bf(val - bf2f(hh));
        }
      }
    }
    #pragma unroll
    for (int m=16;m<64;m<<=1){
      #pragma unroll
      for (int nt=0;nt<4;++nt) csum[nt] += __shfl_xor(csum[nt], m);
    }
    if (qd==0){
      #pragma unroll
      for (int nt=0;nt<4;++nt) scrc[w][(w>>1)*64 + nt*16 + lm] = csum[nt];
    }
    __syncthreads();
    if (tid < 128){
      float s = scrc[0][tid]+scrc[1][tid]+scrc[2][tid]+scrc[3][tid];
      double* dst = (z==0) ? qgs : kgs;
      atomicAdd(&dst[nb*128 + tid], (double)s);
    }
  } else {
    #pragma unroll
    for (int mt=0;mt<2;++mt){
      #pragma unroll
      for (int nt=0;nt<4;++nt){
        #pragma unroll
        for (int i=0;i<4;++i){
          int tglob = mb*64 + rbase + mt*16 + qd*4 + i;
          int qb = tglob>>10, n = tglob&1023;
          int p = head*4 + qb;
          int d = nt*16 + lm;
          fv[((size_t)(p*NTOK+n))*DH + d] = acc[mt][nt][i];
        }
      }
    }
  }
}

// ------------------------------------ transpose fv -> fvT (bf16 hi/lo, [p][d][m])

__global__ __launch_bounds__(256) void k_vT(const float* __restrict__ fv,
    unsigned short* __restrict__ fvTh, unsigned short* __restrict__ fvTl){
  __shared__ float tile[64][65];
  int mc = blockIdx.x, p = blockIdx.y, tid = threadIdx.x;
  #pragma unroll
  for (int it=0; it<4; ++it){
    int idx = tid + 256*it;
    int m = idx>>4, d4 = idx&15;
    float4 vv = *(const float4*)(fv + ((size_t)(p*NTOK + mc*64 + m)*DH + d4*4));
    tile[d4*4+0][m]=vv.x; tile[d4*4+1][m]=vv.y; tile[d4*4+2][m]=vv.z; tile[d4*4+3][m]=vv.w;
  }
  __syncthreads();
  #pragma unroll
  for (int it=0; it<2; ++it){
    int idx = tid + 256*it;       // 0..511
    int d = idx>>3, seg = idx&7;  // 8 m per thread
    size_t base = (size_t)(p*DH + d)*NTOK + mc*64 + seg*8;
    ushort4 h0,h1,l0,l1;
    { float xx=tile[d][seg*8+0]; unsigned short hh=f2bf(xx); h0.x=hh; l0.x=f2bf(xx-bf2f(hh)); }
    { float xx=tile[d][seg*8+1]; unsigned short hh=f2bf(xx); h0.y=hh; l0.y=f2bf(xx-bf2f(hh)); }
    { float xx=tile[d][seg*8+2]; unsigned short hh=f2bf(xx); h0.z=hh; l0.z=f2bf(xx-bf2f(hh)); }
    { float xx=tile[d][seg*8+3]; unsigned short hh=f2bf(xx); h0.w=hh; l0.w=f2bf(xx-bf2f(hh)); }
    { float xx=tile[d][seg*8+4]; unsigned short hh=f2bf(xx); h1.x=hh; l1.x=f2bf(xx-bf2f(hh)); }
    { float xx=tile[d][seg*8+5]; unsigned short hh=f2bf(xx); h1.y=hh; l1.y=f2bf(xx-bf2f(hh)); }
    { float xx=tile[d][seg*8+6]; unsigned short hh=f2bf(xx); h1.z=hh; l1.z=f2bf(xx-bf2f(hh)); }
    { float xx=tile[d][seg*8+7]; unsigned short hh=f2bf(xx); h1.w=hh; l1.w=f2bf(xx-bf2f(hh)); }
    *(ushort4*)(fvTh+base)   = h0;
    *(ushort4*)(fvTh+base+4) = h1;
    *(ushort4*)(fvTl+base)   = l0;
    *(ushort4*)(fvTl+base+4) = l1;
  }
}

// -------------------------------------------- nu (col-means of f_k) and S

__global__ __launch_bounds__(256) void k_nu(const unsigned short* __restrict__ fkh,
    const unsigned short* __restrict__ fkl,
    float* __restrict__ nuA, float* __restrict__ Sarr){
  __shared__ float red[4][64];
  int p = blockIdx.x, tid = threadIdx.x;
  int td = tid & 63, tm = tid >> 6;
  float s = 0.f;
  for (int m = tm; m < NTOK; m += 4){
    size_t ix = (size_t)(p*NTOK+m)*DH + td;
    s += bf2f(fkh[ix]) + bf2f(fkl[ix]);
  }
  red[tm][td] = s;
  __syncthreads();
  if (tid < 64){
    float tot = red[0][tid]+red[1][tid]+red[2][tid]+red[3][tid];
    float nuv = tot * (1.0f/1024.0f);
    nuA[p*DH+tid] = nuv;
    float sv = nuv;
    #pragma unroll
    for (int off=32; off; off>>=1) sv += __shfl_down(sv, off);
    if (tid==0) Sarr[p] = sv;
  }
}

// --------------------------------------- per-row scalars for f_q and f_k

__global__ __launch_bounds__(256) void k_rows(
    const unsigned short* __restrict__ fqh, const unsigned short* __restrict__ fql,
    const unsigned short* __restrict__ fkh, const unsigned short* __restrict__ fkl,
    const float* __restrict__ nuA,
    float* __restrict__ inv_na_q, float* __restrict__ inv_nb_q,
    float* __restrict__ muqA, float* __restrict__ tqA,
    float* __restrict__ inv_na_k, float* __restrict__ inv_nb_k,
    float* __restrict__ skA){
  int wid = threadIdx.x >> 6, lane = threadIdx.x & 63;
  int row = blockIdx.x*4 + wid;            // < 32768
  int p = row >> 10;
  size_t ix = (size_t)row*DH + lane;
  float xq = bf2f(fqh[ix]) + bf2f(fql[ix]);
  float nv = nuA[p*DH + lane];
  float s = xq, ss = xq*xq, sd = xq*nv;
  #pragma unroll
  for (int off=32; off; off>>=1){
    s += __shfl_down(s,off); ss += __shfl_down(ss,off); sd += __shfl_down(sd,off);
  }
  if (lane==0){
    float nrm = sqrtf(ss);
    inv_na_q[row] = 1.0f/(nrm+1e-8f);
    inv_nb_q[row] = 1.0f/fmaxf(nrm,1e-6f);
    muqA[row] = s*(1.0f/64.0f);
    tqA[row] = sd;
  }
  float xk = bf2f(fkh[ix]) + bf2f(fkl[ix]);
  float s2 = xk, ss2 = xk*xk;
  #pragma unroll
  for (int off=32; off; off>>=1){
    s2 += __shfl_down(s2,off); ss2 += __shfl_down(ss2,off);
  }
  if (lane==0){
    float nrm = sqrtf(ss2);
    inv_na_k[row] = 1.0f/(nrm+1e-8f);
    inv_nb_k[row] = 1.0f/fmaxf(nrm,1e-6f);
    skA[row] = s2;
  }
}

// ------------------------------------------------- weight predictor (tiny)

__global__ __launch_bounds__(256) void k_wp(const double* __restrict__ qgs,
    const double* __restrict__ kgs,
    const float* __restrict__ W1, const float* __restrict__ b1,
    const float* __restrict__ lgv, const float* __restrict__ lbv,
    const float* __restrict__ W2, const float* __restrict__ b2,
    const float* __restrict__ W3, const float* __restrict__ b3,
    const float* __restrict__ wtemp, float* __restrict__ wp_out){
  __shared__ float feats[8][128];
  __shared__ float h1[8][64];
  __shared__ float h2s[8][32];
  __shared__ float lgt[8][3];
  __shared__ float mv[8][2];
  int tid = threadIdx.x;
  for (int idx = tid; idx < 1024; idx += 256){
    int h = idx >> 7, i = idx & 127;
    double vv = (i < 64) ? qgs[h*64+i] : kgs[h*64+(i-64)];
    feats[h][i] = (float)(vv * (1.0/4096.0));
  }
  __syncthreads();
  for (int idx = tid; idx < 512; idx += 256){
    int h = idx >> 6, j = idx & 63;
    float s = b1[j];
    for (int i = 0; i < 128; ++i) s += feats[h][i]*W1[i*64+j];
    h1[h][j] = s;
  }
  __syncthreads();
  if (tid < 8){
    float s=0.f, ss=0.f;
    for (int j=0;j<64;++j){ float vv=h1[tid][j]; s+=vv; ss+=vv*vv; }
    float mu = s*(1.0f/64.0f);
    float var = ss*(1.0f/64.0f)-mu*mu;
    mv[tid][0]=mu; mv[tid][1]=1.0f/sqrtf(var+1e-5f);
  }
  __syncthreads();
  for (int idx = tid; idx < 512; idx += 256){
    int h = idx>>6, j = idx&63;
    float vv = (h1[h][j]-mv[h][0])*mv[h][1]*lgv[j] + lbv[j];
    h1[h][j] = fmaxf(vv, 0.f);
  }
  __syncthreads();
  {
    int h = tid >> 5, j = tid & 31;
    float s = b2[j];
    for (int i=0;i<64;++i) s += h1[h][i]*W2[i*32+j];
    h2s[h][j] = fmaxf(s, 0.f);
  }
  __syncthreads();
  if (tid < 24){
    int h = tid/3, j = tid - h*3;
    float s = b3[j];
    for (int i=0;i<32;++i) s += h2s[h][i]*W3[i*3+j];
    lgt[h][j] = s;
  }
  __syncthreads();
  if (tid < 8){
    int h = tid;
    float z0=lgt[h][0], z1=lgt[h][1], z2=lgt[h][2];
    float m = fmaxf(z0,fmaxf(z1,z2));
    float e0=expf(z0-m), e1=expf(z1-m), e2=expf(z2-m);
    float inv = 1.0f/(e0+e1+e2);
    float l0=e0*inv, l1=e1*inv, l2=e2*inv;
    float wt = fminf(fmaxf(wtemp[0], 0.1f), 20.0f);
    float y0=l0/wt, y1=l1/wt, y2=l2/wt;
    float m2 = fmaxf(y0,fmaxf(y1,y2));
    float f0=expf(y0-m2), f1=expf(y1-m2), f2=expf(y2-m2);
    float inv2 = 1.0f/(f0+f1+f2);
    float w0=f0*inv2, w1=f1*inv2, w2=f2*inv2;
    w0 = fminf(fmaxf(w0,0.05f),0.8f);
    w1 = fminf(fmaxf(w1,0.05f),0.8f);
    w2 = fminf(fmaxf(w2,0.05f),0.8f);
    float isum = 1.0f/(w0+w1+w2);
    wp_out[h*3+0]=w0*isum; wp_out[h*3+1]=w1*isum; wp_out[h*3+2]=w2*isum;
  }
}

// ------------------------- pass A (MFMA): QK^T, derive cos/cov/margin, stats

__global__ __launch_bounds__(256) void k_passA(
    const unsigned short* __restrict__ fqh, const unsigned short* __restrict__ fql,
    const unsigned short* __restrict__ fkh, const unsigned short* __restrict__ fkl,
    const float* __restrict__ inv_na_q, const float* __restrict__ inv_nb_q,
    const float* __restrict__ muqA, const float* __restrict__ tqA,
    const float* __restrict__ inv_na_k, const float* __restrict__ inv_nb_k,
    const float* __restrict__ skA, const float* __restrict__ Sarr,
    float* __restrict__ rs_cos, float* __restrict__ rs_cov, float* __restrict__ rs_marg,
    float* __restrict__ mxcosA, float* __restrict__ mncosA,
    float* __restrict__ mxcovA, float* __restrict__ mncovA,
    double* __restrict__ gacc){
  __shared__ float cAs[1024], cBs[1024], cSs[1024];
  __shared__ float redbuf[4][16][8];
  __shared__ double wredS[4][5];
  int b = blockIdx.x, p = b>>5, s = b&31, n0 = s*32;
  int tid = threadIdx.x, w = tid>>6, l = tid&63;
  int rt = w&1, cw = w>>1, lm = l&15, q = l>>4;
  for (int idx = tid; idx < 1024; idx += 256){
    int rg = p*NTOK + idx;
    cAs[idx] = inv_na_k[rg]; cBs[idx] = inv_nb_k[rg]; cSs[idx] = skA[rg];
  }
  float Sp = Sarr[p];
  float ia[4], ib[4], mq[4], tq2[4];
  #pragma unroll
  for (int i=0;i<4;++i){
    int rg = p*NTOK + n0 + rt*16 + q*4 + i;
    ia[i]=inv_na_q[rg]; ib[i]=inv_nb_q[rg]; mq[i]=muqA[rg];
    tq2[i]=tqA[rg] - mq[i]*Sp;
  }
  const short8* aqhp = (const short8*)(fqh + (size_t)(p*NTOK + n0 + rt*16 + lm)*DH);
  const short8* aqlp = (const short8*)(fql + (size_t)(p*NTOK + n0 + rt*16 + lm)*DH);
  short8 ah0 = aqhp[q], ah1 = aqhp[4+q], al0 = aqlp[q], al1 = aqlp[4+q];
  __syncthreads();
  const float inv8 = (float)(1.0/(8.0+1e-6));
  double dc1=0,dc2=0,dv1=0,dv2=0,dcv=0;
  float pc[4]={0,0,0,0}, pv_[4]={0,0,0,0}, pm[4]={0,0,0,0};
  float xc[4], nc[4], xv[4], nv[4];
  #pragma unroll
  for (int i=0;i<4;++i){ xc[i]=-1e30f; nc[i]=1e30f; xv[i]=-1e30f; nv[i]=1e30f; }
  for (int t=0; t<32; ++t){
    int c = cw + 2*t;
    const short8* bhp = (const short8*)(fkh + (size_t)(p*NTOK + c*16 + lm)*DH);
    const short8* blp = (const short8*)(fkl + (size_t)(p*NTOK + c*16 + lm)*DH);
    short8 bh0=bhp[q], bh1=bhp[4+q], bl0=blp[q], bl1=blp[4+q];
    f32x4 acc = {0.f,0.f,0.f,0.f};
    acc = mfma16(ah0,bh0,acc); acc = mfma16(ah1,bh1,acc);
    acc = mfma16(al0,bh0,acc); acc = mfma16(al1,bh1,acc);
    acc = mfma16(ah0,bl0,acc); acc = mfma16(ah1,bl1,acc);
    int col = c*16 + lm;
    float ca=cAs[col], cb=cBs[col], cs=cSs[col];
    float tc1=0.f, tc2=0.f, tv1=0.f, tv2=0.f, tcv=0.f;
    #pragma unroll
    for (int i=0;i<4;++i){
      float dot = acc[i];
      float cosv = fminf(fmaxf(dot*ia[i]*ca,-0.99f),0.99f);
      float csim = fminf(fmaxf(dot*ib[i]*cb,-0.99f),0.99f);
      float marg = fmaxf(0.01f - csim, 0.f);
      float cov  = (dot - tq2[i] - mq[i]*cs)*inv8;
      tc1 += cosv; tc2 = fmaf(cosv,cosv,tc2);
      tv1 += cov;  tv2 = fmaf(cov,cov,tv2);
      tcv = fmaf(cosv,cov,tcv);
      pc[i]+=cosv; pv_[i]+=cov; pm[i]+=marg;
      xc[i]=fmaxf(xc[i],cosv); nc[i]=fminf(nc[i],cosv);
      xv[i]=fmaxf(xv[i],cov);  nv[i]=fminf(nv[i],cov);
    }
    dc1 += (double)tc1; dc2 += (double)tc2;
    dv1 += (double)tv1; dv2 += (double)tv2; dcv += (double)tcv;
  }
  #pragma unroll
  for (int m=1;m<16;m<<=1){
    #pragma unroll
    for (int i=0;i<4;++i){
      pc[i]+=__shfl_xor(pc[i],m); pv_[i]+=__shfl_xor(pv_[i],m); pm[i]+=__shfl_xor(pm[i],m);
      xc[i]=fmaxf(xc[i],__shfl_xor(xc[i],m)); nc[i]=fminf(nc[i],__shfl_xor(nc[i],m));
      xv[i]=fmaxf(xv[i],__shfl_xor(xv[i],m)); nv[i]=fminf(nv[i],__shfl_xor(nv[i],m));
    }
  }
  if (lm==0){
    #pragma unroll
    for (int i=0;i<4;++i){
      int r16 = q*4+i;
      redbuf[w][r16][0]=pc[i]; redbuf[w][r16][1]=pv_[i]; redbuf[w][r16][2]=pm[i];
      redbuf[w][r16][3]=xc[i]; redbuf[w][r16][4]=nc[i];
      redbuf[w][r16][5]=xv[i]; redbuf[w][r16][6]=nv[i];
    }
  }
  double vals[5] = {dc1,dc2,dv1,dv2,dcv};
  #pragma unroll
  for (int c2=0;c2<5;++c2){
    double vv = vals[c2];
    #pragma unroll
    for (int off=32; off; off>>=1) vv += __shfl_down(vv, off);
    if (l==0) wredS[w][c2] = vv;
  }
  __syncthreads();
  if (tid < 32){
    int rt2 = tid>>4, r16 = tid&15;
    int w0 = rt2, w1 = rt2+2;
    float sc = redbuf[w0][r16][0]+redbuf[w1][r16][0];
    float sv = redbuf[w0][r16][1]+redbuf[w1][r16][1];
    float sm = redbuf[w0][r16][2]+redbuf[w1][r16][2];
    float mxc = fmaxf(redbuf[w0][r16][3],redbuf[w1][r16][3]);
    float mnc = fminf(redbuf[w0][r16][4],redbuf[w1][r16][4]);
    float mxv = fmaxf(redbuf[w0][r16][5],redbuf[w1][r16][5]);
    float mnv = fminf(redbuf[w0][r16][6],redbuf[w1][r16][6]);
    int row = p*NTOK + n0 + tid;
    rs_cos[row]=sc; rs_cov[row]=sv; rs_marg[row]=sm;
    mxcosA[row]=mxc; mncosA[row]=mnc; mxcovA[row]=mxv; mncovA[row]=mnv;
  }
  if (tid == 0){
    int h = p >> 2;
    #pragma unroll
    for (int c2=0;c2<5;++c2){
      double t = wredS[0][c2]+wredS[1][c2]+wredS[2][c2]+wredS[3][c2];
      atomicAdd(&gacc[h*5+c2], t);
    }
  }
}

// ---------------------- row finish: var_row + var-related global moments

__global__ __launch_bounds__(256) void k_rowfin(const float* __restrict__ rs_cos,
    const float* __restrict__ rs_cov, const float* __restrict__ rs_marg,
    float* __restrict__ var_row, double* __restrict__ racc){
  __shared__ double wredS[4][4];
  int row = blockIdx.x*256 + threadIdx.x;
  int p = row >> 10; int h = p >> 2;
  float vr = rs_marg[row] * (1.0f/1024.0f);
  var_row[row] = vr;
  double dv = (double)vr;
  double vals[4];
  vals[0] = 1024.0*dv;
  vals[1] = 1024.0*dv*dv;
  vals[2] = dv*(double)rs_cos[row];
  vals[3] = dv*(double)rs_cov[row];
  int lane = threadIdx.x & 63, wid = threadIdx.x >> 6;
  #pragma unroll
  for (int c2 = 0; c2 < 4; ++c2){
    double vv = vals[c2];
    #pragma unroll
    for (int off=32; off; off>>=1) vv += __shfl_down(vv, off);
    if (lane==0) wredS[wid][c2] = vv;
  }
  __syncthreads();
  if (threadIdx.x == 0){
    #pragma unroll
    for (int c2 = 0; c2 < 4; ++c2){
      double t = wredS[0][c2]+wredS[1][c2]+wredS[2][c2]+wredS[3][c2];
      atomicAdd(&racc[h*4+c2], t);
    }
  }
}

// ------------------------------------- finalize scalars -> d2 coefficients

__global__ void k_final(const double* __restrict__ gacc, const double* __restrict__ racc,
                        const float* __restrict__ wp_out, float* __restrict__ coef){
  if (threadIdx.x != 0) return;
  const double N = 33554432.0;
  double Sc1=0,Sc2=0,Sv1=0,Sv2=0,Sr1=0,Sr2=0;
  for (int h=0;h<8;++h){
    Sc1+=gacc[h*5+0]; Sc2+=gacc[h*5+1]; Sv1+=gacc[h*5+2]; Sv2+=gacc[h*5+3];
    Sr1+=racc[h*4+0]; Sr2+=racc[h*4+1];
  }
  double cvar = (Sc2 - Sc1*Sc1/N)/(N-1.0);
  double cn = sqrt(fmax(cvar,0.0)) + 1e-6;
  double cscale = (cn < 1e-4) ? 0.1 : 1.0;
  double vraw = (Sv2 - Sv1*Sv1/N)/(N-1.0);
  double sraw = sqrt(fmax(vraw,0.0));
  double basev = 0.001/1024.0;
  double regv = (sraw < 1e-6) ? basev*10.0 : basev;
  double covn = regv*sraw + 1e-6;
  double vvar = (Sr2 - Sr1*Sr1/N)/(N-1.0);
  double vn = sqrt(fmax(vvar,0.0)) + 1e-6;
  double ah[8], bh[8], chh[8];
  double Sd1=0.0, Sd2=0.0;
  for (int h=0;h<8;++h){
    double a = (double)wp_out[h*3+0]/cn*cscale;
    double b = (double)wp_out[h*3+1]*regv*0.5/covn;
    double c = (double)wp_out[h*3+2]*0.5/vn;
    ah[h]=a; bh[h]=b; chh[h]=c;
    Sd1 += a*gacc[h*5+0] + b*gacc[h*5+2] + c*racc[h*4+0];
    Sd2 += a*a*gacc[h*5+1] + b*b*gacc[h*5+3] + c*c*racc[h*4+1]
         + 2.0*(a*b*gacc[h*5+4] + a*c*racc[h*4+2] + b*c*racc[h*4+3]);
  }
  double dvar = (Sd2 - Sd1*Sd1/N)/(N-1.0);
  double dstd = sqrt(fmax(dvar,0.0));
  double temp = (dstd < 1e-6) ? 0.1 : 0.3 + dstd;
  double tcl = fmin(fmax(temp,0.1),5.0);
  double it = 1.0/tcl;
  for (int h=0;h<8;++h){
    coef[h*3+0] = (float)(ah[h]*it);
    coef[h*3+1] = (float)(bh[h]*it);
    coef[h*3+2] = (float)(chh[h]*it);
  }
}

// -------------------- pass C (MFMA): recompute QK, softmax via bound, PV

__global__ __launch_bounds__(256) void k_pv(
    const unsigned short* __restrict__ fqh, const unsigned short* __restrict__ fql,
    const unsigned short* __restrict__ fkh, const unsigned short* __restrict__ fkl,
    const unsigned short* __restrict__ fvTh, const unsigned short* __restrict__ fvTl,
    const float* __restrict__ inv_na_q, const float* __restrict__ muqA,
    const float* __restrict__ tqA,
    const float* __restrict__ inv_na_k, const float* __restrict__ skA,
    const float* __restrict__ Sarr, const float* __restrict__ var_row,
    const float* __restrict__ mxcosA, const float* __restrict__ mncosA,
    const float* __restrict__ mxcovA, const float* __restrict__ mncovA,
    const float* __restrict__ coef,
    unsigned short* __restrict__ ohh, unsigned short* __restrict__ ohl){
  __shared__ float cAs[1024], cSs[1024];
  __shared__ __align__(16) unsigned short ph[32][72];
  __shared__ __align__(16) unsigned short pl[32][72];
  __shared__ float denbuf[4][16];
  __shared__ float dnv[32];
  int b = blockIdx.x, p = b>>5, s = b&31, n0 = s*32;
  int h = p>>2, qb = p&3;
  int tid = threadIdx.x, w = tid>>6, l = tid&63;
  int rt = w&1, cw = w>>1, lm = l&15, q = l>>4;
  float A = coef[h*3+0], B = coef[h*3+1], C = coef[h*3+2];
  for (int idx = tid; idx < 1024; idx += 256){
    int rg = p*NTOK + idx;
    cAs[idx] = inv_na_k[rg]; cSs[idx] = skA[rg];
  }
  float Sp = Sarr[p];
  float ia[4], mq[4], tq2[4], off[4];
  #pragma unroll
  for (int i=0;i<4;++i){
    int rg = p*NTOK + n0 + rt*16 + q*4 + i;
    ia[i]=inv_na_q[rg]; mq[i]=muqA[rg];
    tq2[i]=tqA[rg] - mq[i]*Sp;
    float vr = var_row[rg];
    float Mh = fmaxf(A*mxcosA[rg],A*mncosA[rg]) + fmaxf(B*mxcovA[rg],B*mncovA[rg]) + C*vr;
    off[i] = C*vr - Mh;
  }
  const short8* aqhp = (const short8*)(fqh + (size_t)(p*NTOK + n0 + rt*16 + lm)*DH);
  const short8* aqlp = (const short8*)(fql + (size_t)(p*NTOK + n0 + rt*16 + lm)*DH);
  short8 ah0 = aqhp[q], ah1 = aqhp[4+q], al0 = aqlp[q], al1 = aqlp[4+q];
  const float inv8 = (float)(1.0/(8.0+1e-6));
  f32x4 o0 = {0.f,0.f,0.f,0.f}, o1 = {0.f,0.f,0.f,0.f};
  float den[4] = {0.f,0.f,0.f,0.f};
  __syncthreads();
  for (int cc = 0; cc < 16; ++cc){
    int m0 = cc*64;
    #pragma unroll
    for (int t2=0;t2<2;++t2){
      int c16 = cw*2 + t2;
      int colg = m0 + c16*16 + lm;
      const short8* bhp = (const short8*)(fkh + (size_t)(p*NTOK + colg)*DH);
      const short8* blp = (const short8*)(fkl + (size_t)(p*NTOK + colg)*DH);
      short8 bh0=bhp[q], bh1=bhp[4+q], bl0=blp[q], bl1=blp[4+q];
      f32x4 acc = {0.f,0.f,0.f,0.f};
      acc = mfma16(ah0,bh0,acc); acc = mfma16(ah1,bh1,acc);
      acc = mfma16(al0,bh0,acc); acc = mfma16(al1,bh1,acc);
      acc = mfma16(ah0,bl0,acc); acc = mfma16(ah1,bl1,acc);
      float ca = cAs[colg], cs = cSs[colg];
      #pragma unroll
      for (int i=0;i<4;++i){
        float dot = acc[i];
        float cosv = fminf(fmaxf(dot*ia[i]*ca,-0.99f),0.99f);
        float cov  = (dot - tq2[i] - mq[i]*cs)*inv8;
        float e = __expf(A*cosv + B*cov + off[i]);
        den[i] += e;
        unsigned short hi = f2bf(e);
        unsigned short lo = f2bf(e - bf2f(hi));
        ph[rt*16+q*4+i][c16*16+lm] = hi;
        pl[rt*16+q*4+i][c16*16+lm] = lo;
      }
    }
    __syncthreads();
    const short8* avh = (const short8*)(fvTh + ((size_t)(p*DH + w*16 + lm)*NTOK + m0));
    const short8* avl = (const short8*)(fvTl + ((size_t)(p*DH + w*16 + lm)*NTOK + m0));
    #pragma unroll
    for (int kk=0;kk<2;++kk){
      short8 ahv = avh[kk*4+q], alv = avl[kk*4+q];
      short8 b0h = *(const short8*)(&ph[lm][kk*32+q*8]);
      short8 b0l = *(const short8*)(&pl[lm][kk*32+q*8]);
      short8 b1h = *(const short8*)(&ph[16+lm][kk*32+q*8]);
      short8 b1l = *(const short8*)(&pl[16+lm][kk*32+q*8]);
      o0 = mfma16(ahv,b0h,o0); o0 = mfma16(ahv,b0l,o0); o0 = mfma16(alv,b0h,o0);
      o1 = mfma16(ahv,b1h,o1); o1 = mfma16(ahv,b1l,o1); o1 = mfma16(alv,b1h,o1);
    }
    __syncthreads();
  }
  #pragma unroll
  for (int m=1;m<16;m<<=1){
    #pragma unroll
    for (int i=0;i<4;++i) den[i] += __shfl_xor(den[i],m);
  }
  if (lm==0){
    #pragma unroll
    for (int i=0;i<4;++i) denbuf[w][q*4+i] = den[i];
  }
  __syncthreads();
  if (tid < 32){
    int rt2 = tid>>4, r16 = tid&15;
    dnv[tid] = 1.0f/(denbuf[rt2][r16] + denbuf[rt2+2][r16]);
  }
  __syncthreads();
  {
    float inv0 = dnv[lm];
    float inv1 = dnv[16+lm];
    int d0 = w*16 + q*4;
    size_t b0i = ((size_t)(qb*NTOK + n0 + lm))*(NH*DH) + h*DH + d0;
    size_t b1i = ((size_t)(qb*NTOK + n0 + 16 + lm))*(NH*DH) + h*DH + d0;
    ushort4 h0,l0,h1,l1;
    { float xx=o0[0]*inv0; unsigned short hh=f2bf(xx); h0.x=hh; l0.x=f2bf(xx-bf2f(hh)); }
    { float xx=o0[1]*inv0; unsigned short hh=f2bf(xx); h0.y=hh; l0.y=f2bf(xx-bf2f(hh)); }
    { float xx=o0[2]*inv0; unsigned short hh=f2bf(xx); h0.z=hh; l0.z=f2bf(xx-bf2f(hh)); }
    { float xx=o0[3]*inv0; unsigned short hh=f2bf(xx); h0.w=hh; l0.w=f2bf(xx-bf2f(hh)); }
    { float xx=o1[0]*inv1; unsigned short hh=f2bf(xx); h1.x=hh; l1.x=f2bf(xx-bf2f(hh)); }
    { float xx=o1[1]*inv1; unsigned short hh=f2bf(xx); h1.y=hh; l1.y=f2bf(xx-bf2f(hh)); }
    { float xx=o1[2]*inv1; unsigned short hh=f2bf(xx); h1.z=hh; l1.z=f2bf(xx-bf2f(hh)); }
    { float xx=o1[3]*inv1; unsigned short hh=f2bf(xx); h1.w=hh; l1.w=f2bf(xx-bf2f(hh)); }
    *(ushort4*)(ohh+b0i)=h0; *(ushort4*)(ohl+b0i)=l0;
    *(ushort4*)(ohh+b1i)=h1; *(ushort4*)(ohl+b1i)=l1;
  }
}

// ----------------- output GEMM (MFMA, no LDS): oh @ W_out + b -> out

__global__ __launch_bounds__(256) void k_outmm(
    const unsigned short* __restrict__ ohh, const unsigned short* __restrict__ ohl,
    const unsigned short* __restrict__ Woth, const unsigned short* __restrict__ Wotl,
    const float* __restrict__ bias, float* __restrict__ out){
  int mb = blockIdx.x, nb = blockIdx.y;
  int tid = threadIdx.x, w = tid>>6, l = tid&63, lm = l&15, qd = l>>4;
  int rbase = mb*64 + (w&1)*32;
  int cbase = nb*128 + (w>>1)*64;
  f32x4 acc[2][4];
  #pragma unroll
  for (int mt=0;mt<2;++mt)
    #pragma unroll
    for (int nt=0;nt<4;++nt) acc[mt][nt] = (f32x4){0.f,0.f,0.f,0.f};
  for (int kc=0; kc<16; ++kc){
    short8 a_h[2], a_l[2];
    #pragma unroll
    for (int mt=0;mt<2;++mt){
      size_t aix = (size_t)(rbase+mt*16+lm)*DIMX + kc*32 + qd*8;
      a_h[mt] = *(const short8*)(ohh + aix);
      a_l[mt] = *(const short8*)(ohl + aix);
    }
    #pragma unroll
    for (int nt=0;nt<4;++nt){
      size_t wix = (size_t)(cbase+nt*16+lm)*DIMX + kc*32 + qd*8;
      short8 bh = *(const short8*)(Woth + wix);
      short8 bl = *(const short8*)(Wotl + wix);
      #pragma unroll
      for (int mt=0;mt<2;++mt){
        acc[mt][nt] = mfma16(a_h[mt], bh, acc[mt][nt]);
        acc[mt][nt] = mfma16(a_h[mt], bl, acc[mt][nt]);
        acc[mt][nt] = mfma16(a_l[mt], bh, acc[mt][nt]);
      }
    }
  }
  float bv[4];
  #pragma unroll
  for (int nt=0;nt<4;++nt) bv[nt] = bias[cbase+nt*16+lm];
  #pragma unroll
  for (int mt=0;mt<2;++mt){
    #pragma unroll
    for (int i=0;i<4;++i){
      int row = rbase + mt*16 + qd*4 + i;
      #pragma unroll
      for (int nt=0;nt<4;++nt){
        out[(size_t)row*DIMX + cbase + nt*16 + lm] = acc[mt][nt][i] + bv[nt];
      }
    }
  }
}

// ----------------------------------------------------------------- launch

extern "C" void kernel_launch(void* const* d_in, const int* in_sizes, int n_in,
                              void* d_out, int out_size, void* d_ws, size_t ws_size,
                              hipStream_t stream) {
  (void)in_sizes; (void)n_in; (void)out_size;
  const float* q     = (const float*)d_in[0];
  const float* k     = (const float*)d_in[1];
  const float* v     = (const float*)d_in[2];
  const float* ln_g  = (const float*)d_in[3];
  const float* ln_b  = (const float*)d_in[4];
  const float* W_in  = (const float*)d_in[5];
  const float* wp_W1 = (const float*)d_in[6];
  const float* wp_b1 = (const float*)d_in[7];
  const float* wp_lg = (const float*)d_in[8];
  const float* wp_lb = (const float*)d_in[9];
  const float* wp_W2 = (const float*)d_in[10];
  const float* wp_b2 = (const float*)d_in[11];
  const float* wp_W3 = (const float*)d_in[12];
  const float* wp_b3 = (const float*)d_in[13];
  const float* wtemp = (const float*)d_in[14];
  const float* W_out = (const float*)d_in[15];
  const float* b_out = (const float*)d_in[16];
  float* out = (float*)d_out;

  char* wsb = (char*)d_ws;
  double* gacc = (double*)wsb;            // 40 doubles
  double* racc = gacc + 40;               // 32
  double* qgs  = racc + 32;               // 512
  double* kgs  = qgs + 512;               // 512  (zone0 total 8768 B < 16384)
  float* fvA = (float*)(wsb + 16384);     // 2M floats (8 MB); reused as ohh/ohl after k_vT
  unsigned short* ohh = (unsigned short*)fvA;                   // 4 MB
  unsigned short* ohl = ohh + (size_t)NQB*NTOK*NH*DH;           // 4 MB
  float* mu_rstd = fvA + (size_t)NPAIR*NTOK*DH;   // 24576
  float* nuA  = mu_rstd + 24576;          // 2048
  float* Sarr = nuA + 2048;               // 64 (padded)
  float* inv_na_q = Sarr + 64;
  float* inv_nb_q = inv_na_q + NROWS;
  float* muqA     = inv_nb_q + NROWS;
  float* tqA      = muqA + NROWS;
  float* inv_na_k = tqA + NROWS;
  float* inv_nb_k = inv_na_k + NROWS;
  float* skA      = inv_nb_k + NROWS;
  float* rs_cos   = skA + NROWS;
  float* rs_cov   = rs_cos + NROWS;
  float* rs_marg  = rs_cov + NROWS;
  float* var_row  = rs_marg + NROWS;
  float* mxcos    = var_row + NROWS;
  float* mncos    = mxcos + NROWS;
  float* mxcov    = mncos + NROWS;
  float* mncov    = mxcov + NROWS;
  float* wp_out   = mncov + NROWS;        // 32 (padded)
  float* coef     = wp_out + 32;          // 32 (padded)
  float* endf     = coef + 32;
  size_t off16 = (size_t)((char*)endf - wsb);
  off16 = (off16 + 63) & ~(size_t)63;
  unsigned short* fqh  = (unsigned short*)(wsb + off16);
  unsigned short* fql  = fqh  + (size_t)NPAIR*NTOK*DH;
  unsigned short* fkh  = fql  + (size_t)NPAIR*NTOK*DH;
  unsigned short* fkl  = fkh  + (size_t)NPAIR*NTOK*DH;
  unsigned short* fvTh = fkl  + (size_t)NPAIR*NTOK*DH;
  unsigned short* fvTl = fvTh + (size_t)NPAIR*NTOK*DH;
  unsigned short* Wth  = fvTl + (size_t)NPAIR*NTOK*DH;
  unsigned short* Wtl  = Wth  + (size_t)DIMX*DIMX;
  unsigned short* Woth = Wtl  + (size_t)DIMX*DIMX;
  unsigned short* Wotl = Woth + (size_t)DIMX*DIMX;
  size_t need = (size_t)((char*)(Wotl + (size_t)DIMX*DIMX) - wsb);
  if (ws_size < need) return;  // fail cleanly rather than corrupt

  hipMemsetAsync(wsb, 0, 16384, stream);
  k_lnstats<<<3072, 256, 0, stream>>>(q, k, v, mu_rstd);
  k_splitW<<<dim3(8,8,2), 256, 0, stream>>>(W_in, W_out, Wth, Wtl, Woth, Wotl);
  k_projmm<<<dim3(64,4,3), 256, 0, stream>>>(q, k, v, ln_g, ln_b, Wth, Wtl,
                                             mu_rstd, fqh, fql, fkh, fkl, fvA,
                                             qgs, kgs);
  k_vT<<<dim3(16,32), 256, 0, stream>>>(fvA, fvTh, fvTl);
  k_nu<<<32, 256, 0, stream>>>(fkh, fkl, nuA, Sarr);
  k_rows<<<8192, 256, 0, stream>>>(fqh, fql, fkh, fkl, nuA,
                                   inv_na_q, inv_nb_q, muqA, tqA,
                                   inv_na_k, inv_nb_k, skA);
  k_wp<<<1, 256, 0, stream>>>(qgs, kgs, wp_W1, wp_b1, wp_lg, wp_lb,
                              wp_W2, wp_b2, wp_W3, wp_b3, wtemp, wp_out);
  k_passA<<<1024, 256, 0, stream>>>(fqh, fql, fkh, fkl,
                                    inv_na_q, inv_nb_q, muqA, tqA,
                                    inv_na_k, inv_nb_k, skA, Sarr,
                                    rs_cos, rs_cov, rs_marg,
                                    mxcos, mncos, mxcov, mncov, gacc);
  k_rowfin<<<128, 256, 0, stream>>>(rs_cos, rs_cov, rs_marg, var_row, racc);
  k_final<<<1, 64, 0, stream>>>(gacc, racc, wp_out, coef);
  k_pv<<<1024, 256, 0, stream>>>(fqh, fql, fkh, fkl, fvTh, fvTl,
                                 inv_na_q, muqA, tqA, inv_na_k, skA, Sarr,
                                 var_row, mxcos, mncos, mxcov, mncov, coef,
                                 ohh, ohl);
  k_outmm<<<dim3(64,4), 256, 0, stream>>>(ohh, ohl, Woth, Wotl, b_out, out);
}

// Round 4
// 482.375 us; speedup vs baseline: 1.5334x; 1.0133x over previous
//
#include <hip/hip_runtime.h>
#include <math.h>

#define NH    8
#define NQB   4
#define NPAIR 32
#define NTOK  1024
#define DH    64
#define DIMX  512
#define NROWS (NPAIR*NTOK)

typedef __attribute__((ext_vector_type(8))) short short8;
typedef __attribute__((ext_vector_type(4))) float f32x4;

__device__ __forceinline__ unsigned short f2bf(float x){
  unsigned u = __float_as_uint(x);
  u += 0x7fffu + ((u>>16)&1u);
  return (unsigned short)(u>>16);
}
__device__ __forceinline__ float bf2f(unsigned short h){
  return __uint_as_float(((unsigned)h)<<16);
}
__device__ __forceinline__ f32x4 mfma16(short8 a, short8 b, f32x4 c){
  return __builtin_amdgcn_mfma_f32_16x16x32_bf16(a,b,c,0,0,0);
}

// ------------------------------------------------- per-token LN statistics

__global__ __launch_bounds__(256) void k_lnstats(const float* __restrict__ q,
    const float* __restrict__ k, const float* __restrict__ v,
    float* __restrict__ mu_rstd){
  int wid = threadIdx.x >> 6, lane = threadIdx.x & 63;
  int tok = blockIdx.x*4 + wid;            // 0..12287
  const float* src = (tok < 4096) ? q : ((tok < 8192) ? k : v);
  int t = tok & 4095;
  const float4* p4 = (const float4*)(src + (size_t)t*DIMX) + lane*2;
  float4 a = p4[0], b = p4[1];
  float s  = a.x+a.y+a.z+a.w + b.x+b.y+b.z+b.w;
  float ss = a.x*a.x+a.y*a.y+a.z*a.z+a.w*a.w
           + b.x*b.x+b.y*b.y+b.z*b.z+b.w*b.w;
  #pragma unroll
  for (int off=32; off; off>>=1){ s += __shfl_down(s,off); ss += __shfl_down(ss,off); }
  if (lane==0){
    float mu = s*(1.0f/512.0f);
    float var = ss*(1.0f/512.0f) - mu*mu;
    mu_rstd[tok*2+0] = mu;
    mu_rstd[tok*2+1] = 1.0f/sqrtf(var + 1e-5f);
  }
}

// ---------------- transpose + hi/lo split of W_in and W_out -> [n][k] bf16

__global__ __launch_bounds__(256) void k_splitW(const float* __restrict__ Wa,
    const float* __restrict__ Wb,
    unsigned short* __restrict__ Wth, unsigned short* __restrict__ Wtl,
    unsigned short* __restrict__ Woth, unsigned short* __restrict__ Wotl){
  __shared__ float tile[64][65];
  int z = blockIdx.z;
  const float* W = z ? Wb : Wa;
  unsigned short* oh_ = z ? Woth : Wth;
  unsigned short* ol_ = z ? Wotl : Wtl;
  int kb = blockIdx.x, nb = blockIdx.y, tid = threadIdx.x;
  #pragma unroll
  for (int it=0; it<4; ++it){
    int idx = tid + 256*it;          // 0..1023
    int kr = idx>>4, c4 = idx&15;
    float4 vv = *(const float4*)(W + (size_t)(kb*64+kr)*DIMX + nb*64 + c4*4);
    tile[c4*4+0][kr]=vv.x; tile[c4*4+1][kr]=vv.y; tile[c4*4+2][kr]=vv.z; tile[c4*4+3][kr]=vv.w;
  }
  __syncthreads();
  #pragma unroll
  for (int it=0; it<4; ++it){
    int idx = tid + 256*it;
    int n = idx>>4, k4 = idx&15;
    size_t base = (size_t)(nb*64+n)*DIMX + kb*64 + k4*4;
    ushort4 hv, lv;
    { float xx=tile[n][k4*4+0]; unsigned short hh=f2bf(xx); hv.x=hh; lv.x=f2bf(xx-bf2f(hh)); }
    { float xx=tile[n][k4*4+1]; unsigned short hh=f2bf(xx); hv.y=hh; lv.y=f2bf(xx-bf2f(hh)); }
    { float xx=tile[n][k4*4+2]; unsigned short hh=f2bf(xx); hv.z=hh; lv.z=f2bf(xx-bf2f(hh)); }
    { float xx=tile[n][k4*4+3]; unsigned short hh=f2bf(xx); hv.w=hh; lv.w=f2bf(xx-bf2f(hh)); }
    *(ushort4*)(oh_+base) = hv;
    *(ushort4*)(ol_+base) = lv;
  }
}

// --------------- LN + projection GEMM via split-bf16 MFMA (q, k, v by z)

__global__ __launch_bounds__(256) void k_projmm(
    const float* __restrict__ q, const float* __restrict__ k, const float* __restrict__ v,
    const float* __restrict__ g, const float* __restrict__ bln,
    const unsigned short* __restrict__ Wth, const unsigned short* __restrict__ Wtl,
    const float* __restrict__ mu_rstd,
    unsigned short* __restrict__ fqh, unsigned short* __restrict__ fql,
    unsigned short* __restrict__ fkh, unsigned short* __restrict__ fkl,
    float* __restrict__ fv,
    double* __restrict__ qgs, double* __restrict__ kgs){
  __shared__ __align__(16) unsigned short Ahs[64*72];
  __shared__ __align__(16) unsigned short Als[64*72];
  __shared__ float scrc[4][128];
  int z = blockIdx.z;
  const float* x = (z==0) ? q : ((z==1) ? k : v);
  int mb = blockIdx.x, nb = blockIdx.y;
  int tid = threadIdx.x, w = tid>>6, l = tid&63, lm = l&15, qd = l>>4;
  int rbase = (w&1)*32;
  int cbase = nb*128 + (w>>1)*64;
  scrc[tid>>7][tid&127] = 0.f;
  scrc[2+(tid>>7)][tid&127] = 0.f;
  f32x4 acc[2][4];
  #pragma unroll
  for (int mt=0;mt<2;++mt)
    #pragma unroll
    for (int nt=0;nt<4;++nt) acc[mt][nt] = (f32x4){0.f,0.f,0.f,0.f};
  for (int kc8 = 0; kc8 < 8; ++kc8){
    // stage 64 rows x 64 k, LN'd, split hi/lo
    float4 xv[4]; float mus[4], rss[4]; float4 gv[4], bv[4]; int rr[4], kk4[4];
    #pragma unroll
    for (int it=0; it<4; ++it){
      int idx = tid + 256*it;          // 0..1023
      int r = idx>>4, k4 = idx&15;
      rr[it]=r; kk4[it]=k4;
      int tokg = z*4096 + mb*64 + r;
      mus[it] = mu_rstd[tokg*2+0]; rss[it] = mu_rstd[tokg*2+1];
      xv[it] = *(const float4*)(x + (size_t)(mb*64+r)*DIMX + kc8*64 + k4*4);
      gv[it] = *(const float4*)(g   + kc8*64 + k4*4);
      bv[it] = *(const float4*)(bln + kc8*64 + k4*4);
    }
    __syncthreads();   // previous iteration's reads complete
    #pragma unroll
    for (int it=0; it<4; ++it){
      float y0 = (xv[it].x-mus[it])*rss[it]*gv[it].x + bv[it].x;
      float y1 = (xv[it].y-mus[it])*rss[it]*gv[it].y + bv[it].y;
      float y2 = (xv[it].z-mus[it])*rss[it]*gv[it].z + bv[it].z;
      float y3 = (xv[it].w-mus[it])*rss[it]*gv[it].w + bv[it].w;
      ushort4 hv, lv;
      { unsigned short hh=f2bf(y0); hv.x=hh; lv.x=f2bf(y0-bf2f(hh)); }
      { unsigned short hh=f2bf(y1); hv.y=hh; lv.y=f2bf(y1-bf2f(hh)); }
      { unsigned short hh=f2bf(y2); hv.z=hh; lv.z=f2bf(y2-bf2f(hh)); }
      { unsigned short hh=f2bf(y3); hv.w=hh; lv.w=f2bf(y3-bf2f(hh)); }
      *(ushort4*)(Ahs + rr[it]*72 + kk4[it]*4) = hv;
      *(ushort4*)(Als + rr[it]*72 + kk4[it]*4) = lv;
    }
    __syncthreads();
    #pragma unroll
    for (int kch=0; kch<2; ++kch){
      short8 a_h[2], a_l[2];
      #pragma unroll
      for (int mt=0;mt<2;++mt){
        a_h[mt] = *(const short8*)(Ahs + (rbase+mt*16+lm)*72 + kch*32 + qd*8);
        a_l[mt] = *(const short8*)(Als + (rbase+mt*16+lm)*72 + kch*32 + qd*8);
      }
      #pragma unroll
      for (int nt=0;nt<4;++nt){
        int cg = cbase + nt*16 + lm;
        size_t wix = (size_t)cg*DIMX + kc8*64 + kch*32 + qd*8;
        short8 bh = *(const short8*)(Wth + wix);
        short8 bl = *(const short8*)(Wtl + wix);
        #pragma unroll
        for (int mt=0;mt<2;++mt){
          acc[mt][nt] = mfma16(a_h[mt], bh, acc[mt][nt]);
          acc[mt][nt] = mfma16(a_h[mt], bl, acc[mt][nt]);
          acc[mt][nt] = mfma16(a_l[mt], bh, acc[mt][nt]);
        }
      }
    }
  }
  // epilogue
  int head = cbase >> 6;               // = nb*2 + (w>>1)
  if (z < 2){
    unsigned short* hd = (z==0) ? fqh : fkh;
    unsigned short* ld_ = (z==0) ? fql : fkl;
    float csum[4] = {0.f,0.f,0.f,0.f};
    #pragma unroll
    for (int mt=0;mt<2;++mt){
      #pragma unroll
      for (int nt=0;nt<4;++nt){
        #pragma unroll
        for (int i=0;i<4;++i){
          float val = acc[mt][nt][i];
          csum[nt] += val;
          int tglob = mb*64 + rbase + mt*16 + qd*4 + i;
          int qb = tglob>>10, n = tglob&1023;
          int p = head*4 + qb;
          int d = nt*16 + lm;
          size_t ix = ((size_t)(p*NTOK+n))*DH + d;
          unsigned short hh = f2bf(val);
          hd[ix] = hh; ld_[ix] = f2bf(val - bf2f(hh));
        }
      }
    }
    #pragma unroll
    for (int m=16;m<64;m<<=1){
      #pragma unroll
      for (int nt=0;nt<4;++nt) csum[nt] += __shfl_xor(csum[nt], m);
    }
    if (qd==0){
      #pragma unroll
      for (int nt=0;nt<4;++nt) scrc[w][(w>>1)*64 + nt*16 + lm] = csum[nt];
    }
    __syncthreads();
    if (tid < 128){
      float s = scrc[0][tid]+scrc[1][tid]+scrc[2][tid]+scrc[3][tid];
      double* dst = (z==0) ? qgs : kgs;
      atomicAdd(&dst[nb*128 + tid], (double)s);
    }
  } else {
    #pragma unroll
    for (int mt=0;mt<2;++mt){
      #pragma unroll
      for (int nt=0;nt<4;++nt){
        #pragma unroll
        for (int i=0;i<4;++i){
          int tglob = mb*64 + rbase + mt*16 + qd*4 + i;
          int qb = tglob>>10, n = tglob&1023;
          int p = head*4 + qb;
          int d = nt*16 + lm;
          fv[((size_t)(p*NTOK+n))*DH + d] = acc[mt][nt][i];
        }
      }
    }
  }
}

// ------------------------------------ transpose fv -> fvT (bf16 hi/lo, [p][d][m])

__global__ __launch_bounds__(256) void k_vT(const float* __restrict__ fv,
    unsigned short* __restrict__ fvTh, unsigned short* __restrict__ fvTl){
  __shared__ float tile[64][65];
  int mc = blockIdx.x, p = blockIdx.y, tid = threadIdx.x;
  #pragma unroll
  for (int it=0; it<4; ++it){
    int idx = tid + 256*it;
    int m = idx>>4, d4 = idx&15;
    float4 vv = *(const float4*)(fv + ((size_t)(p*NTOK + mc*64 + m)*DH + d4*4));
    tile[d4*4+0][m]=vv.x; tile[d4*4+1][m]=vv.y; tile[d4*4+2][m]=vv.z; tile[d4*4+3][m]=vv.w;
  }
  __syncthreads();
  #pragma unroll
  for (int it=0; it<2; ++it){
    int idx = tid + 256*it;       // 0..511
    int d = idx>>3, seg = idx&7;  // 8 m per thread
    size_t base = (size_t)(p*DH + d)*NTOK + mc*64 + seg*8;
    ushort4 h0,h1,l0,l1;
    { float xx=tile[d][seg*8+0]; unsigned short hh=f2bf(xx); h0.x=hh; l0.x=f2bf(xx-bf2f(hh)); }
    { float xx=tile[d][seg*8+1]; unsigned short hh=f2bf(xx); h0.y=hh; l0.y=f2bf(xx-bf2f(hh)); }
    { float xx=tile[d][seg*8+2]; unsigned short hh=f2bf(xx); h0.z=hh; l0.z=f2bf(xx-bf2f(hh)); }
    { float xx=tile[d][seg*8+3]; unsigned short hh=f2bf(xx); h0.w=hh; l0.w=f2bf(xx-bf2f(hh)); }
    { float xx=tile[d][seg*8+4]; unsigned short hh=f2bf(xx); h1.x=hh; l1.x=f2bf(xx-bf2f(hh)); }
    { float xx=tile[d][seg*8+5]; unsigned short hh=f2bf(xx); h1.y=hh; l1.y=f2bf(xx-bf2f(hh)); }
    { float xx=tile[d][seg*8+6]; unsigned short hh=f2bf(xx); h1.z=hh; l1.z=f2bf(xx-bf2f(hh)); }
    { float xx=tile[d][seg*8+7]; unsigned short hh=f2bf(xx); h1.w=hh; l1.w=f2bf(xx-bf2f(hh)); }
    *(ushort4*)(fvTh+base)   = h0;
    *(ushort4*)(fvTh+base+4) = h1;
    *(ushort4*)(fvTl+base)   = l0;
    *(ushort4*)(fvTl+base+4) = l1;
  }
}

// -------------------------------------------- nu (col-means of f_k) and S

__global__ __launch_bounds__(256) void k_nu(const unsigned short* __restrict__ fkh,
    const unsigned short* __restrict__ fkl,
    float* __restrict__ nuA, float* __restrict__ Sarr){
  __shared__ float red[4][64];
  int p = blockIdx.x, tid = threadIdx.x;
  int td = tid & 63, tm = tid >> 6;
  float s = 0.f;
  for (int m = tm; m < NTOK; m += 4){
    size_t ix = (size_t)(p*NTOK+m)*DH + td;
    s += bf2f(fkh[ix]) + bf2f(fkl[ix]);
  }
  red[tm][td] = s;
  __syncthreads();
  if (tid < 64){
    float tot = red[0][tid]+red[1][tid]+red[2][tid]+red[3][tid];
    float nuv = tot * (1.0f/1024.0f);
    nuA[p*DH+tid] = nuv;
    float sv = nuv;
    #pragma unroll
    for (int off=32; off; off>>=1) sv += __shfl_down(sv, off);
    if (tid==0) Sarr[p] = sv;
  }
}

// --------------------------------------- per-row scalars for f_q and f_k

__global__ __launch_bounds__(256) void k_rows(
    const unsigned short* __restrict__ fqh, const unsigned short* __restrict__ fql,
    const unsigned short* __restrict__ fkh, const unsigned short* __restrict__ fkl,
    const float* __restrict__ nuA,
    float* __restrict__ inv_na_q, float* __restrict__ inv_nb_q,
    float* __restrict__ muqA, float* __restrict__ tqA,
    float* __restrict__ inv_na_k, float* __restrict__ inv_nb_k,
    float* __restrict__ skA){
  int wid = threadIdx.x >> 6, lane = threadIdx.x & 63;
  int row = blockIdx.x*4 + wid;            // < 32768
  int p = row >> 10;
  size_t ix = (size_t)row*DH + lane;
  float xq = bf2f(fqh[ix]) + bf2f(fql[ix]);
  float nv = nuA[p*DH + lane];
  float s = xq, ss = xq*xq, sd = xq*nv;
  #pragma unroll
  for (int off=32; off; off>>=1){
    s += __shfl_down(s,off); ss += __shfl_down(ss,off); sd += __shfl_down(sd,off);
  }
  if (lane==0){
    float nrm = sqrtf(ss);
    inv_na_q[row] = 1.0f/(nrm+1e-8f);
    inv_nb_q[row] = 1.0f/fmaxf(nrm,1e-6f);
    muqA[row] = s*(1.0f/64.0f);
    tqA[row] = sd;
  }
  float xk = bf2f(fkh[ix]) + bf2f(fkl[ix]);
  float s2 = xk, ss2 = xk*xk;
  #pragma unroll
  for (int off=32; off; off>>=1){
    s2 += __shfl_down(s2,off); ss2 += __shfl_down(ss2,off);
  }
  if (lane==0){
    float nrm = sqrtf(ss2);
    inv_na_k[row] = 1.0f/(nrm+1e-8f);
    inv_nb_k[row] = 1.0f/fmaxf(nrm,1e-6f);
    skA[row] = s2;
  }
}

// ------------------------------------------------- weight predictor (tiny)

__global__ __launch_bounds__(256) void k_wp(const double* __restrict__ qgs,
    const double* __restrict__ kgs,
    const float* __restrict__ W1, const float* __restrict__ b1,
    const float* __restrict__ lgv, const float* __restrict__ lbv,
    const float* __restrict__ W2, const float* __restrict__ b2,
    const float* __restrict__ W3, const float* __restrict__ b3,
    const float* __restrict__ wtemp, float* __restrict__ wp_out){
  __shared__ float feats[8][128];
  __shared__ float h1[8][64];
  __shared__ float h2s[8][32];
  __shared__ float lgt[8][3];
  __shared__ float mv[8][2];
  int tid = threadIdx.x;
  for (int idx = tid; idx < 1024; idx += 256){
    int h = idx >> 7, i = idx & 127;
    double vv = (i < 64) ? qgs[h*64+i] : kgs[h*64+(i-64)];
    feats[h][i] = (float)(vv * (1.0/4096.0));
  }
  __syncthreads();
  for (int idx = tid; idx < 512; idx += 256){
    int h = idx >> 6, j = idx & 63;
    float s = b1[j];
    for (int i = 0; i < 128; ++i) s += feats[h][i]*W1[i*64+j];
    h1[h][j] = s;
  }
  __syncthreads();
  if (tid < 8){
    float s=0.f, ss=0.f;
    for (int j=0;j<64;++j){ float vv=h1[tid][j]; s+=vv; ss+=vv*vv; }
    float mu = s*(1.0f/64.0f);
    float var = ss*(1.0f/64.0f)-mu*mu;
    mv[tid][0]=mu; mv[tid][1]=1.0f/sqrtf(var+1e-5f);
  }
  __syncthreads();
  for (int idx = tid; idx < 512; idx += 256){
    int h = idx>>6, j = idx&63;
    float vv = (h1[h][j]-mv[h][0])*mv[h][1]*lgv[j] + lbv[j];
    h1[h][j] = fmaxf(vv, 0.f);
  }
  __syncthreads();
  {
    int h = tid >> 5, j = tid & 31;
    float s = b2[j];
    for (int i=0;i<64;++i) s += h1[h][i]*W2[i*32+j];
    h2s[h][j] = fmaxf(s, 0.f);
  }
  __syncthreads();
  if (tid < 24){
    int h = tid/3, j = tid - h*3;
    float s = b3[j];
    for (int i=0;i<32;++i) s += h2s[h][i]*W3[i*3+j];
    lgt[h][j] = s;
  }
  __syncthreads();
  if (tid < 8){
    int h = tid;
    float z0=lgt[h][0], z1=lgt[h][1], z2=lgt[h][2];
    float m = fmaxf(z0,fmaxf(z1,z2));
    float e0=expf(z0-m), e1=expf(z1-m), e2=expf(z2-m);
    float inv = 1.0f/(e0+e1+e2);
    float l0=e0*inv, l1=e1*inv, l2=e2*inv;
    float wt = fminf(fmaxf(wtemp[0], 0.1f), 20.0f);
    float y0=l0/wt, y1=l1/wt, y2=l2/wt;
    float m2 = fmaxf(y0,fmaxf(y1,y2));
    float f0=expf(y0-m2), f1=expf(y1-m2), f2=expf(y2-m2);
    float inv2 = 1.0f/(f0+f1+f2);
    float w0=f0*inv2, w1=f1*inv2, w2=f2*inv2;
    w0 = fminf(fmaxf(w0,0.05f),0.8f);
    w1 = fminf(fmaxf(w1,0.05f),0.8f);
    w2 = fminf(fmaxf(w2,0.05f),0.8f);
    float isum = 1.0f/(w0+w1+w2);
    wp_out[h*3+0]=w0*isum; wp_out[h*3+1]=w1*isum; wp_out[h*3+2]=w2*isum;
  }
}

// ------------------------- pass A (MFMA): QK^T, derive cos/cov/margin, stats
// XCD-swizzled: same-p blocks colocate on one XCD (4 pairs per XCD fit L2)

__global__ __launch_bounds__(256) void k_passA(
    const unsigned short* __restrict__ fqh, const unsigned short* __restrict__ fql,
    const unsigned short* __restrict__ fkh, const unsigned short* __restrict__ fkl,
    const float* __restrict__ inv_na_q, const float* __restrict__ inv_nb_q,
    const float* __restrict__ muqA, const float* __restrict__ tqA,
    const float* __restrict__ inv_na_k, const float* __restrict__ inv_nb_k,
    const float* __restrict__ skA, const float* __restrict__ Sarr,
    float* __restrict__ rs_cos, float* __restrict__ rs_cov, float* __restrict__ rs_marg,
    float* __restrict__ mxcosA, float* __restrict__ mncosA,
    float* __restrict__ mxcovA, float* __restrict__ mncovA,
    double* __restrict__ gacc){
  __shared__ float cAs[1024], cBs[1024], cSs[1024];
  __shared__ float redbuf[4][16][8];
  __shared__ double wredS[4][5];
  int b = blockIdx.x;
  int p = ((b&7)<<2) | ((b>>3)&3);   // XCD swizzle: b%8 constant per p
  int s = b>>5;
  int n0 = s*32;
  int tid = threadIdx.x, w = tid>>6, l = tid&63;
  int rt = w&1, cw = w>>1, lm = l&15, q = l>>4;
  for (int idx = tid; idx < 1024; idx += 256){
    int rg = p*NTOK + idx;
    cAs[idx] = inv_na_k[rg]; cBs[idx] = inv_nb_k[rg]; cSs[idx] = skA[rg];
  }
  float Sp = Sarr[p];
  float ia[4], ib[4], mq[4], tq2[4];
  #pragma unroll
  for (int i=0;i<4;++i){
    int rg = p*NTOK + n0 + rt*16 + q*4 + i;
    ia[i]=inv_na_q[rg]; ib[i]=inv_nb_q[rg]; mq[i]=muqA[rg];
    tq2[i]=tqA[rg] - mq[i]*Sp;
  }
  const short8* aqhp = (const short8*)(fqh + (size_t)(p*NTOK + n0 + rt*16 + lm)*DH);
  const short8* aqlp = (const short8*)(fql + (size_t)(p*NTOK + n0 + rt*16 + lm)*DH);
  short8 ah0 = aqhp[q], ah1 = aqhp[4+q], al0 = aqlp[q], al1 = aqlp[4+q];
  const unsigned short* fkb_h = fkh + (size_t)p*NTOK*DH;
  const unsigned short* fkb_l = fkl + (size_t)p*NTOK*DH;
  __syncthreads();
  const float inv8 = (float)(1.0/(8.0+1e-6));
  double dc1=0,dc2=0,dv1=0,dv2=0,dcv=0;
  float pc[4]={0,0,0,0}, pv_[4]={0,0,0,0}, pm[4]={0,0,0,0};
  float xc[4], nc[4], xv[4], nv[4];
  #pragma unroll
  for (int i=0;i<4;++i){ xc[i]=-1e30f; nc[i]=1e30f; xv[i]=-1e30f; nv[i]=1e30f; }
  // prefetch tile 0
  short8 nbh0, nbh1, nbl0, nbl1;
  {
    const short8* bhp = (const short8*)(fkb_h + (size_t)(cw*16+lm)*DH);
    const short8* blp = (const short8*)(fkb_l + (size_t)(cw*16+lm)*DH);
    nbh0=bhp[q]; nbh1=bhp[4+q]; nbl0=blp[q]; nbl1=blp[4+q];
  }
  for (int t=0; t<32; ++t){
    int c = cw + 2*t;
    short8 bh0=nbh0, bh1=nbh1, bl0=nbl0, bl1=nbl1;
    if (t < 31){
      int c2 = c + 2;
      const short8* bhp = (const short8*)(fkb_h + (size_t)(c2*16+lm)*DH);
      const short8* blp = (const short8*)(fkb_l + (size_t)(c2*16+lm)*DH);
      nbh0=bhp[q]; nbh1=bhp[4+q]; nbl0=blp[q]; nbl1=blp[4+q];
    }
    f32x4 acc = {0.f,0.f,0.f,0.f};
    acc = mfma16(ah0,bh0,acc); acc = mfma16(ah1,bh1,acc);
    acc = mfma16(al0,bh0,acc); acc = mfma16(al1,bh1,acc);
    acc = mfma16(ah0,bl0,acc); acc = mfma16(ah1,bl1,acc);
    int col = c*16 + lm;
    float ca=cAs[col], cb=cBs[col], cs=cSs[col];
    float tc1=0.f, tc2=0.f, tv1=0.f, tv2=0.f, tcv=0.f;
    #pragma unroll
    for (int i=0;i<4;++i){
      float dot = acc[i];
      float cosv = fminf(fmaxf(dot*ia[i]*ca,-0.99f),0.99f);
      float csim = fminf(fmaxf(dot*ib[i]*cb,-0.99f),0.99f);
      float marg = fmaxf(0.01f - csim, 0.f);
      float cov  = (dot - tq2[i] - mq[i]*cs)*inv8;
      tc1 += cosv; tc2 = fmaf(cosv,cosv,tc2);
      tv1 += cov;  tv2 = fmaf(cov,cov,tv2);
      tcv = fmaf(cosv,cov,tcv);
      pc[i]+=cosv; pv_[i]+=cov; pm[i]+=marg;
      xc[i]=fmaxf(xc[i],cosv); nc[i]=fminf(nc[i],cosv);
      xv[i]=fmaxf(xv[i],cov);  nv[i]=fminf(nv[i],cov);
    }
    dc1 += (double)tc1; dc2 += (double)tc2;
    dv1 += (double)tv1; dv2 += (double)tv2; dcv += (double)tcv;
  }
  #pragma unroll
  for (int m=1;m<16;m<<=1){
    #pragma unroll
    for (int i=0;i<4;++i){
      pc[i]+=__shfl_xor(pc[i],m); pv_[i]+=__shfl_xor(pv_[i],m); pm[i]+=__shfl_xor(pm[i],m);
      xc[i]=fmaxf(xc[i],__shfl_xor(xc[i],m)); nc[i]=fminf(nc[i],__shfl_xor(nc[i],m));
      xv[i]=fmaxf(xv[i],__shfl_xor(xv[i],m)); nv[i]=fminf(nv[i],__shfl_xor(nv[i],m));
    }
  }
  if (lm==0){
    #pragma unroll
    for (int i=0;i<4;++i){
      int r16 = q*4+i;
      redbuf[w][r16][0]=pc[i]; redbuf[w][r16][1]=pv_[i]; redbuf[w][r16][2]=pm[i];
      redbuf[w][r16][3]=xc[i]; redbuf[w][r16][4]=nc[i];
      redbuf[w][r16][5]=xv[i]; redbuf[w][r16][6]=nv[i];
    }
  }
  double vals[5] = {dc1,dc2,dv1,dv2,dcv};
  #pragma unroll
  for (int c2=0;c2<5;++c2){
    double vv = vals[c2];
    #pragma unroll
    for (int off=32; off; off>>=1) vv += __shfl_down(vv, off);
    if (l==0) wredS[w][c2] = vv;
  }
  __syncthreads();
  if (tid < 32){
    int rt2 = tid>>4, r16 = tid&15;
    int w0 = rt2, w1 = rt2+2;
    float sc = redbuf[w0][r16][0]+redbuf[w1][r16][0];
    float sv = redbuf[w0][r16][1]+redbuf[w1][r16][1];
    float sm = redbuf[w0][r16][2]+redbuf[w1][r16][2];
    float mxc = fmaxf(redbuf[w0][r16][3],redbuf[w1][r16][3]);
    float mnc = fminf(redbuf[w0][r16][4],redbuf[w1][r16][4]);
    float mxv = fmaxf(redbuf[w0][r16][5],redbuf[w1][r16][5]);
    float mnv = fminf(redbuf[w0][r16][6],redbuf[w1][r16][6]);
    int row = p*NTOK + n0 + tid;
    rs_cos[row]=sc; rs_cov[row]=sv; rs_marg[row]=sm;
    mxcosA[row]=mxc; mncosA[row]=mnc; mxcovA[row]=mxv; mncovA[row]=mnv;
  }
  if (tid == 0){
    int h = p >> 2;
    #pragma unroll
    for (int c2=0;c2<5;++c2){
      double t = wredS[0][c2]+wredS[1][c2]+wredS[2][c2]+wredS[3][c2];
      atomicAdd(&gacc[h*5+c2], t);
    }
  }
}

// ---------------------- row finish: var_row + var-related global moments

__global__ __launch_bounds__(256) void k_rowfin(const float* __restrict__ rs_cos,
    const float* __restrict__ rs_cov, const float* __restrict__ rs_marg,
    float* __restrict__ var_row, double* __restrict__ racc){
  __shared__ double wredS[4][4];
  int row = blockIdx.x*256 + threadIdx.x;
  int p = row >> 10; int h = p >> 2;
  float vr = rs_marg[row] * (1.0f/1024.0f);
  var_row[row] = vr;
  double dv = (double)vr;
  double vals[4];
  vals[0] = 1024.0*dv;
  vals[1] = 1024.0*dv*dv;
  vals[2] = dv*(double)rs_cos[row];
  vals[3] = dv*(double)rs_cov[row];
  int lane = threadIdx.x & 63, wid = threadIdx.x >> 6;
  #pragma unroll
  for (int c2 = 0; c2 < 4; ++c2){
    double vv = vals[c2];
    #pragma unroll
    for (int off=32; off; off>>=1) vv += __shfl_down(vv, off);
    if (lane==0) wredS[wid][c2] = vv;
  }
  __syncthreads();
  if (threadIdx.x == 0){
    #pragma unroll
    for (int c2 = 0; c2 < 4; ++c2){
      double t = wredS[0][c2]+wredS[1][c2]+wredS[2][c2]+wredS[3][c2];
      atomicAdd(&racc[h*4+c2], t);
    }
  }
}

// ------------------------------------- finalize scalars -> d2 coefficients

__global__ void k_final(const double* __restrict__ gacc, const double* __restrict__ racc,
                        const float* __restrict__ wp_out, float* __restrict__ coef){
  if (threadIdx.x != 0) return;
  const double N = 33554432.0;
  double Sc1=0,Sc2=0,Sv1=0,Sv2=0,Sr1=0,Sr2=0;
  for (int h=0;h<8;++h){
    Sc1+=gacc[h*5+0]; Sc2+=gacc[h*5+1]; Sv1+=gacc[h*5+2]; Sv2+=gacc[h*5+3];
    Sr1+=racc[h*4+0]; Sr2+=racc[h*4+1];
  }
  double cvar = (Sc2 - Sc1*Sc1/N)/(N-1.0);
  double cn = sqrt(fmax(cvar,0.0)) + 1e-6;
  double cscale = (cn < 1e-4) ? 0.1 : 1.0;
  double vraw = (Sv2 - Sv1*Sv1/N)/(N-1.0);
  double sraw = sqrt(fmax(vraw,0.0));
  double basev = 0.001/1024.0;
  double regv = (sraw < 1e-6) ? basev*10.0 : basev;
  double covn = regv*sraw + 1e-6;
  double vvar = (Sr2 - Sr1*Sr1/N)/(N-1.0);
  double vn = sqrt(fmax(vvar,0.0)) + 1e-6;
  double ah[8], bh[8], chh[8];
  double Sd1=0.0, Sd2=0.0;
  for (int h=0;h<8;++h){
    double a = (double)wp_out[h*3+0]/cn*cscale;
    double b = (double)wp_out[h*3+1]*regv*0.5/covn;
    double c = (double)wp_out[h*3+2]*0.5/vn;
    ah[h]=a; bh[h]=b; chh[h]=c;
    Sd1 += a*gacc[h*5+0] + b*gacc[h*5+2] + c*racc[h*4+0];
    Sd2 += a*a*gacc[h*5+1] + b*b*gacc[h*5+3] + c*c*racc[h*4+1]
         + 2.0*(a*b*gacc[h*5+4] + a*c*racc[h*4+2] + b*c*racc[h*4+3]);
  }
  double dvar = (Sd2 - Sd1*Sd1/N)/(N-1.0);
  double dstd = sqrt(fmax(dvar,0.0));
  double temp = (dstd < 1e-6) ? 0.1 : 0.3 + dstd;
  double tcl = fmin(fmax(temp,0.1),5.0);
  double it = 1.0/tcl;
  for (int h=0;h<8;++h){
    coef[h*3+0] = (float)(ah[h]*it);
    coef[h*3+1] = (float)(bh[h]*it);
    coef[h*3+2] = (float)(chh[h]*it);
  }
}

// -------------------- pass C (MFMA): recompute QK, softmax via bound, PV
// XCD-swizzled; double-buffered P (1 barrier/iter); prefetched K fragments

__global__ __launch_bounds__(256) void k_pv(
    const unsigned short* __restrict__ fqh, const unsigned short* __restrict__ fql,
    const unsigned short* __restrict__ fkh, const unsigned short* __restrict__ fkl,
    const unsigned short* __restrict__ fvTh, const unsigned short* __restrict__ fvTl,
    const float* __restrict__ inv_na_q, const float* __restrict__ muqA,
    const float* __restrict__ tqA,
    const float* __restrict__ inv_na_k, const float* __restrict__ skA,
    const float* __restrict__ Sarr, const float* __restrict__ var_row,
    const float* __restrict__ mxcosA, const float* __restrict__ mncosA,
    const float* __restrict__ mxcovA, const float* __restrict__ mncovA,
    const float* __restrict__ coef,
    unsigned short* __restrict__ ohh, unsigned short* __restrict__ ohl){
  __shared__ float cAs[1024], cSs[1024];
  __shared__ __align__(16) unsigned short ph[2][32][76];
  __shared__ __align__(16) unsigned short pl[2][32][76];
  __shared__ float denbuf[4][16];
  __shared__ float dnv[32];
  int b = blockIdx.x;
  int p = ((b&7)<<2) | ((b>>3)&3);   // XCD swizzle
  int s = b>>5;
  int n0 = s*32;
  int h = p>>2, qb = p&3;
  int tid = threadIdx.x, w = tid>>6, l = tid&63;
  int rt = w&1, cw = w>>1, lm = l&15, q = l>>4;
  float A = coef[h*3+0], B = coef[h*3+1], C = coef[h*3+2];
  for (int idx = tid; idx < 1024; idx += 256){
    int rg = p*NTOK + idx;
    cAs[idx] = inv_na_k[rg]; cSs[idx] = skA[rg];
  }
  float Sp = Sarr[p];
  float ia[4], mq[4], tq2[4], off[4];
  #pragma unroll
  for (int i=0;i<4;++i){
    int rg = p*NTOK + n0 + rt*16 + q*4 + i;
    ia[i]=inv_na_q[rg]; mq[i]=muqA[rg];
    tq2[i]=tqA[rg] - mq[i]*Sp;
    float vr = var_row[rg];
    float Mh = fmaxf(A*mxcosA[rg],A*mncosA[rg]) + fmaxf(B*mxcovA[rg],B*mncovA[rg]) + C*vr;
    off[i] = C*vr - Mh;
  }
  const short8* aqhp = (const short8*)(fqh + (size_t)(p*NTOK + n0 + rt*16 + lm)*DH);
  const short8* aqlp = (const short8*)(fql + (size_t)(p*NTOK + n0 + rt*16 + lm)*DH);
  short8 ah0 = aqhp[q], ah1 = aqhp[4+q], al0 = aqlp[q], al1 = aqlp[4+q];
  const unsigned short* fkb_h = fkh + (size_t)p*NTOK*DH;
  const unsigned short* fkb_l = fkl + (size_t)p*NTOK*DH;
  const unsigned short* fvb_h = fvTh + (size_t)(p*DH + w*16 + lm)*NTOK;
  const unsigned short* fvb_l = fvTl + (size_t)(p*DH + w*16 + lm)*NTOK;
  const float inv8 = (float)(1.0/(8.0+1e-6));
  f32x4 o0 = {0.f,0.f,0.f,0.f}, o1 = {0.f,0.f,0.f,0.f};
  float den[4] = {0.f,0.f,0.f,0.f};
  // prefetch K frags for cc=0, t2=0 (this wave's first column block: col = cw*32+lm)
  short8 ka_h0, ka_h1, ka_l0, ka_l1;
  {
    const short8* bp_h = (const short8*)(fkb_h + (size_t)(cw*32+lm)*DH);
    const short8* bp_l = (const short8*)(fkb_l + (size_t)(cw*32+lm)*DH);
    ka_h0=bp_h[q]; ka_h1=bp_h[4+q]; ka_l0=bp_l[q]; ka_l1=bp_l[4+q];
  }
  __syncthreads();
  for (int cc = 0; cc < 16; ++cc){
    int m0 = cc*64;
    int buf = cc & 1;
    // V frag loads for this cc (used after barrier; in flight during QK)
    const short8* avh = (const short8*)(fvb_h + m0);
    const short8* avl = (const short8*)(fvb_l + m0);
    short8 v_h0 = avh[q], v_h1 = avh[4+q], v_l0 = avl[q], v_l1 = avl[4+q];
    // t2=1 K frags
    short8 kb_h0, kb_h1, kb_l0, kb_l1;
    {
      int colr = m0 + (cw*2+1)*16 + lm;
      const short8* bp_h = (const short8*)(fkb_h + (size_t)colr*DH);
      const short8* bp_l = (const short8*)(fkb_l + (size_t)colr*DH);
      kb_h0=bp_h[q]; kb_h1=bp_h[4+q]; kb_l0=bp_l[q]; kb_l1=bp_l[4+q];
    }
    // ---- QK t2=0 (current ka_*)
    {
      int c16 = cw*2;
      int colg = m0 + c16*16 + lm;
      f32x4 acc = {0.f,0.f,0.f,0.f};
      acc = mfma16(ah0,ka_h0,acc); acc = mfma16(ah1,ka_h1,acc);
      acc = mfma16(al0,ka_h0,acc); acc = mfma16(al1,ka_h1,acc);
      acc = mfma16(ah0,ka_l0,acc); acc = mfma16(ah1,ka_l1,acc);
      float ca = cAs[colg], cs = cSs[colg];
      #pragma unroll
      for (int i=0;i<4;++i){
        float dot = acc[i];
        float cosv = fminf(fmaxf(dot*ia[i]*ca,-0.99f),0.99f);
        float cov  = (dot - tq2[i] - mq[i]*cs)*inv8;
        float e = __expf(A*cosv + B*cov + off[i]);
        den[i] += e;
        unsigned short hi = f2bf(e);
        unsigned short lo = f2bf(e - bf2f(hi));
        ph[buf][rt*16+q*4+i][c16*16+lm] = hi;
        pl[buf][rt*16+q*4+i][c16*16+lm] = lo;
      }
    }
    // prefetch next iteration's t2=0 K frags
    if (cc < 15){
      int colr = m0 + 64 + cw*32 + lm;
      const short8* bp_h = (const short8*)(fkb_h + (size_t)colr*DH);
      const short8* bp_l = (const short8*)(fkb_l + (size_t)colr*DH);
      ka_h0=bp_h[q]; ka_h1=bp_h[4+q]; ka_l0=bp_l[q]; ka_l1=bp_l[4+q];
    }
    // ---- QK t2=1 (kb_*)
    {
      int c16 = cw*2+1;
      int colg = m0 + c16*16 + lm;
      f32x4 acc = {0.f,0.f,0.f,0.f};
      acc = mfma16(ah0,kb_h0,acc); acc = mfma16(ah1,kb_h1,acc);
      acc = mfma16(al0,kb_h0,acc); acc = mfma16(al1,kb_h1,acc);
      acc = mfma16(ah0,kb_l0,acc); acc = mfma16(ah1,kb_l1,acc);
      float ca = cAs[colg], cs = cSs[colg];
      #pragma unroll
      for (int i=0;i<4;++i){
        float dot = acc[i];
        float cosv = fminf(fmaxf(dot*ia[i]*ca,-0.99f),0.99f);
        float cov  = (dot - tq2[i] - mq[i]*cs)*inv8;
        float e = __expf(A*cosv + B*cov + off[i]);
        den[i] += e;
        unsigned short hi = f2bf(e);
        unsigned short lo = f2bf(e - bf2f(hi));
        ph[buf][rt*16+q*4+i][c16*16+lm] = hi;
        pl[buf][rt*16+q*4+i][c16*16+lm] = lo;
      }
    }
    __syncthreads();
    // ---- PV: O^T += V^T (A) x P^T (B from LDS)   [double-buffered: no 2nd barrier]
    #pragma unroll
    for (int kk=0;kk<2;++kk){
      short8 ahv = kk ? v_h1 : v_h0;
      short8 alv = kk ? v_l1 : v_l0;
      short8 b0h = *(const short8*)(&ph[buf][lm][kk*32+q*8]);
      short8 b0l = *(const short8*)(&pl[buf][lm][kk*32+q*8]);
      short8 b1h = *(const short8*)(&ph[buf][16+lm][kk*32+q*8]);
      short8 b1l = *(const short8*)(&pl[buf][16+lm][kk*32+q*8]);
      o0 = mfma16(ahv,b0h,o0); o0 = mfma16(ahv,b0l,o0); o0 = mfma16(alv,b0h,o0);
      o1 = mfma16(ahv,b1h,o1); o1 = mfma16(ahv,b1l,o1); o1 = mfma16(alv,b1h,o1);
    }
  }
  #pragma unroll
  for (int m=1;m<16;m<<=1){
    #pragma unroll
    for (int i=0;i<4;++i) den[i] += __shfl_xor(den[i],m);
  }
  if (lm==0){
    #pragma unroll
    for (int i=0;i<4;++i) denbuf[w][q*4+i] = den[i];
  }
  __syncthreads();
  if (tid < 32){
    int rt2 = tid>>4, r16 = tid&15;
    dnv[tid] = 1.0f/(denbuf[rt2][r16] + denbuf[rt2+2][r16]);
  }
  __syncthreads();
  {
    float inv0 = dnv[lm];
    float inv1 = dnv[16+lm];
    int d0 = w*16 + q*4;
    size_t b0i = ((size_t)(qb*NTOK + n0 + lm))*(NH*DH) + h*DH + d0;
    size_t b1i = ((size_t)(qb*NTOK + n0 + 16 + lm))*(NH*DH) + h*DH + d0;
    ushort4 h0,l0,h1,l1;
    { float xx=o0[0]*inv0; unsigned short hh=f2bf(xx); h0.x=hh; l0.x=f2bf(xx-bf2f(hh)); }
    { float xx=o0[1]*inv0; unsigned short hh=f2bf(xx); h0.y=hh; l0.y=f2bf(xx-bf2f(hh)); }
    { float xx=o0[2]*inv0; unsigned short hh=f2bf(xx); h0.z=hh; l0.z=f2bf(xx-bf2f(hh)); }
    { float xx=o0[3]*inv0; unsigned short hh=f2bf(xx); h0.w=hh; l0.w=f2bf(xx-bf2f(hh)); }
    { float xx=o1[0]*inv1; unsigned short hh=f2bf(xx); h1.x=hh; l1.x=f2bf(xx-bf2f(hh)); }
    { float xx=o1[1]*inv1; unsigned short hh=f2bf(xx); h1.y=hh; l1.y=f2bf(xx-bf2f(hh)); }
    { float xx=o1[2]*inv1; unsigned short hh=f2bf(xx); h1.z=hh; l1.z=f2bf(xx-bf2f(hh)); }
    { float xx=o1[3]*inv1; unsigned short hh=f2bf(xx); h1.w=hh; l1.w=f2bf(xx-bf2f(hh)); }
    *(ushort4*)(ohh+b0i)=h0; *(ushort4*)(ohl+b0i)=l0;
    *(ushort4*)(ohh+b1i)=h1; *(ushort4*)(ohl+b1i)=l1;
  }
}

// ----------------- output GEMM (MFMA, no LDS): oh @ W_out + b -> out

__global__ __launch_bounds__(256) void k_outmm(
    const unsigned short* __restrict__ ohh, const unsigned short* __restrict__ ohl,
    const unsigned short* __restrict__ Woth, const unsigned short* __restrict__ Wotl,
    const float* __restrict__ bias, float* __restrict__ out){
  int mb = blockIdx.x, nb = blockIdx.y;
  int tid = threadIdx.x, w = tid>>6, l = tid&63, lm = l&15, qd = l>>4;
  int rbase = mb*64 + (w&1)*32;
  int cbase = nb*128 + (w>>1)*64;
  f32x4 acc[2][4];
  #pragma unroll
  for (int mt=0;mt<2;++mt)
    #pragma unroll
    for (int nt=0;nt<4;++nt) acc[mt][nt] = (f32x4){0.f,0.f,0.f,0.f};
  for (int kc=0; kc<16; ++kc){
    short8 a_h[2], a_l[2];
    #pragma unroll
    for (int mt=0;mt<2;++mt){
      size_t aix = (size_t)(rbase+mt*16+lm)*DIMX + kc*32 + qd*8;
      a_h[mt] = *(const short8*)(ohh + aix);
      a_l[mt] = *(const short8*)(ohl + aix);
    }
    #pragma unroll
    for (int nt=0;nt<4;++nt){
      size_t wix = (size_t)(cbase+nt*16+lm)*DIMX + kc*32 + qd*8;
      short8 bh = *(const short8*)(Woth + wix);
      short8 bl = *(const short8*)(Wotl + wix);
      #pragma unroll
      for (int mt=0;mt<2;++mt){
        acc[mt][nt] = mfma16(a_h[mt], bh, acc[mt][nt]);
        acc[mt][nt] = mfma16(a_h[mt], bl, acc[mt][nt]);
        acc[mt][nt] = mfma16(a_l[mt], bh, acc[mt][nt]);
      }
    }
  }
  float bv[4];
  #pragma unroll
  for (int nt=0;nt<4;++nt) bv[nt] = bias[cbase+nt*16+lm];
  #pragma unroll
  for (int mt=0;mt<2;++mt){
    #pragma unroll
    for (int i=0;i<4;++i){
      int row = rbase + mt*16 + qd*4 + i;
      #pragma unroll
      for (int nt=0;nt<4;++nt){
        out[(size_t)row*DIMX + cbase + nt*16 + lm] = acc[mt][nt][i] + bv[nt];
      }
    }
  }
}

// ----------------------------------------------------------------- launch

extern "C" void kernel_launch(void* const* d_in, const int* in_sizes, int n_in,
                              void* d_out, int out_size, void* d_ws, size_t ws_size,
                              hipStream_t stream) {
  (void)in_sizes; (void)n_in; (void)out_size;
  const float* q     = (const float*)d_in[0];
  const float* k     = (const float*)d_in[1];
  const float* v     = (const float*)d_in[2];
  const float* ln_g  = (const float*)d_in[3];
  const float* ln_b  = (const float*)d_in[4];
  const float* W_in  = (const float*)d_in[5];
  const float* wp_W1 = (const float*)d_in[6];
  const float* wp_b1 = (const float*)d_in[7];
  const float* wp_lg = (const float*)d_in[8];
  const float* wp_lb = (const float*)d_in[9];
  const float* wp_W2 = (const float*)d_in[10];
  const float* wp_b2 = (const float*)d_in[11];
  const float* wp_W3 = (const float*)d_in[12];
  const float* wp_b3 = (const float*)d_in[13];
  const float* wtemp = (const float*)d_in[14];
  const float* W_out = (const float*)d_in[15];
  const float* b_out = (const float*)d_in[16];
  float* out = (float*)d_out;

  char* wsb = (char*)d_ws;
  double* gacc = (double*)wsb;            // 40 doubles
  double* racc = gacc + 40;               // 32
  double* qgs  = racc + 32;               // 512
  double* kgs  = qgs + 512;               // 512  (zone0 total 8768 B < 16384)
  float* fvA = (float*)(wsb + 16384);     // 2M floats (8 MB); reused as ohh/ohl after k_vT
  unsigned short* ohh = (unsigned short*)fvA;                   // 4 MB
  unsigned short* ohl = ohh + (size_t)NQB*NTOK*NH*DH;           // 4 MB
  float* mu_rstd = fvA + (size_t)NPAIR*NTOK*DH;   // 24576
  float* nuA  = mu_rstd + 24576;          // 2048
  float* Sarr = nuA + 2048;               // 64 (padded)
  float* inv_na_q = Sarr + 64;
  float* inv_nb_q = inv_na_q + NROWS;
  float* muqA     = inv_nb_q + NROWS;
  float* tqA      = muqA + NROWS;
  float* inv_na_k = tqA + NROWS;
  float* inv_nb_k = inv_na_k + NROWS;
  float* skA      = inv_nb_k + NROWS;
  float* rs_cos   = skA + NROWS;
  float* rs_cov   = rs_cos + NROWS;
  float* rs_marg  = rs_cov + NROWS;
  float* var_row  = rs_marg + NROWS;
  float* mxcos    = var_row + NROWS;
  float* mncos    = mxcos + NROWS;
  float* mxcov    = mncos + NROWS;
  float* mncov    = mxcov + NROWS;
  float* wp_out   = mncov + NROWS;        // 32 (padded)
  float* coef     = wp_out + 32;          // 32 (padded)
  float* endf     = coef + 32;
  size_t off16 = (size_t)((char*)endf - wsb);
  off16 = (off16 + 63) & ~(size_t)63;
  unsigned short* fqh  = (unsigned short*)(wsb + off16);
  unsigned short* fql  = fqh  + (size_t)NPAIR*NTOK*DH;
  unsigned short* fkh  = fql  + (size_t)NPAIR*NTOK*DH;
  unsigned short* fkl  = fkh  + (size_t)NPAIR*NTOK*DH;
  unsigned short* fvTh = fkl  + (size_t)NPAIR*NTOK*DH;
  unsigned short* fvTl = fvTh + (size_t)NPAIR*NTOK*DH;
  unsigned short* Wth  = fvTl + (size_t)NPAIR*NTOK*DH;
  unsigned short* Wtl  = Wth  + (size_t)DIMX*DIMX;
  unsigned short* Woth = Wtl  + (size_t)DIMX*DIMX;
  unsigned short* Wotl = Woth + (size_t)DIMX*DIMX;
  size_t need = (size_t)((char*)(Wotl + (size_t)DIMX*DIMX) - wsb);
  if (ws_size < need) return;  // fail cleanly rather than corrupt

  hipMemsetAsync(wsb, 0, 16384, stream);
  k_lnstats<<<3072, 256, 0, stream>>>(q, k, v, mu_rstd);
  k_splitW<<<dim3(8,8,2), 256, 0, stream>>>(W_in, W_out, Wth, Wtl, Woth, Wotl);
  k_projmm<<<dim3(64,4,3), 256, 0, stream>>>(q, k, v, ln_g, ln_b, Wth, Wtl,
                                             mu_rstd, fqh, fql, fkh, fkl, fvA,
                                             qgs, kgs);
  k_vT<<<dim3(16,32), 256, 0, stream>>>(fvA, fvTh, fvTl);
  k_nu<<<32, 256, 0, stream>>>(fkh, fkl, nuA, Sarr);
  k_rows<<<8192, 256, 0, stream>>>(fqh, fql, fkh, fkl, nuA,
                                   inv_na_q, inv_nb_q, muqA, tqA,
                                   inv_na_k, inv_nb_k, skA);
  k_wp<<<1, 256, 0, stream>>>(qgs, kgs, wp_W1, wp_b1, wp_lg, wp_lb,
                              wp_W2, wp_b2, wp_W3, wp_b3, wtemp, wp_out);
  k_passA<<<1024, 256, 0, stream>>>(fqh, fql, fkh, fkl,
                                    inv_na_q, inv_nb_q, muqA, tqA,
                                    inv_na_k, inv_nb_k, skA, Sarr,
                                    rs_cos, rs_cov, rs_marg,
                                    mxcos, mncos, mxcov, mncov, gacc);
  k_rowfin<<<128, 256, 0, stream>>>(rs_cos, rs_cov, rs_marg, var_row, racc);
  k_final<<<1, 64, 0, stream>>>(gacc, racc, wp_out, coef);
  k_pv<<<1024, 256, 0, stream>>>(fqh, fql, fkh, fkl, fvTh, fvTl,
                                 inv_na_q, muqA, tqA, inv_na_k, skA, Sarr,
                                 var_row, mxcos, mncos, mxcov, mncov, coef,
                                 ohh, ohl);
  k_outmm<<<dim3(64,4), 256, 0, stream>>>(ohh, ohl, Woth, Wotl, b_out, out);
}